// Round 1
// baseline (864.526 us; speedup 1.0000x reference)
//
#include <hip/hip_runtime.h>
#include <hip/hip_bf16.h>
#include <math.h>

// Problem constants
#define N_ATOMS   50000
#define N_EDGES   800000
#define KDIM      192
#define BN_EPS    1e-5f

#define TILE_E     64
#define TPB        5                       // tiles per block (fallback pass)
#define NTILES     (N_EDGES / TILE_E)      // 12500
#define GRID1      (NTILES / TPB)          // 2500 (fallback grid)
#define STAT_SLOTS 32
#define ZSTRIDE    200   // bf16 elems per z row (fallback LDS staging)
#define NSCANBLK   ((N_ATOMS + 255) / 256) // 196

// Direct-gather pass-1 geometry
#define NGROUPS   (N_EDGES / 16)           // 50000 16-edge groups
#define GRID_DIR  768                      // 3 blocks/CU * 256 CUs (all-resident)
#define GSTRIDE   (GRID_DIR * 4)           // 3072 waves total
#define WLSTRIDE  200                      // LDS weight row stride (bank spread)

typedef __attribute__((ext_vector_type(8))) __bf16 bf16x8;
typedef __attribute__((ext_vector_type(4))) float  f32x4;
typedef __attribute__((ext_vector_type(4))) unsigned short u16x4;
typedef __attribute__((ext_vector_type(8))) unsigned short u16x8;
typedef __attribute__((ext_vector_type(4))) unsigned int   u32x4;

__device__ __forceinline__ ushort f2bf(float f) {
    union { float f; unsigned u; } v; v.f = f;
    unsigned u = v.u;
    return (ushort)((u + 0x7FFFu + ((u >> 16) & 1u)) >> 16);
}
__device__ __forceinline__ float bf2f(unsigned hi16) {
    union { unsigned u; float f; } v; v.u = hi16 << 16; return v.f;
}
// BN + sigmoid*softplus message from packed (core | filter<<16) bf16 pair
__device__ __forceinline__ float msgf(unsigned pv, float sc_c, float sh_c,
                                      float sc_f, float sh_f) {
    float pc = fmaf(bf2f(pv & 0xFFFFu), sc_c, sh_c);
    float pf = fmaf(bf2f(pv >> 16),     sc_f, sh_f);
    float sp = fmaxf(pc, 0.f) + __logf(1.f + __expf(-fabsf(pc)));
    float sg = 1.f / (1.f + __expf(-pf));
    return sp * sg;
}

// ---------------------------------------------------------------------------
// Pass 1 (new): weights in LDS, z gathered DIRECTLY into registers per wave.
// Each wave owns disjoint 16-edge groups (strided by GSTRIDE) and computes all
// 128 output cols for them. No per-tile barriers; eidx/perm prefetched 2
// groups ahead, z gathers 1 group ahead -> continuous MLP per wave.
// Pre-act rows stored PERMUTED to CSR slots (perm[e]) for the reduce pass.
// ---------------------------------------------------------------------------
__global__ __launch_bounds__(256, 3) void gemm_stats_direct(
    const float* __restrict__ atom, const float* __restrict__ edgef,
    const ushort* __restrict__ Wb, const int* __restrict__ eidx,
    const unsigned* __restrict__ perm,
    float* __restrict__ stat_partial, unsigned* __restrict__ ws_pre,
    int do_store)
{
    __shared__ __align__(16) ushort Wl[128 * WLSTRIDE];   // 51.2 KB
    const int tid  = threadIdx.x;
    const int lane = tid & 63;
    const int r    = lane & 15;      // MFMA row slot (out-col within 16 / edge row for A)
    const int q    = lane >> 4;      // MFMA k-chunk / C-row group

    // --- stage weights to LDS (once; only barrier in the kernel) ---
    {
        const int row = tid >> 1, half = tid & 1;       // 2 threads per W-row
        const ushort* srcW = Wb + (size_t)row * KDIM + half * 96;
        ushort*       dstW = Wl + row * WLSTRIDE + half * 96;
#pragma unroll
        for (int j = 0; j < 12; ++j)
            *(u16x8*)&dstW[j * 8] = *(const u16x8*)&srcW[j * 8];
    }
    __syncthreads();

    const int wave  = tid >> 6;
    const int wglob = blockIdx.x * 4 + wave;              // 0..GSTRIDE-1
    const int NG    = (NGROUPS - wglob + GSTRIDE - 1) / GSTRIDE;  // 16 or 17

    float s[2][4], qs[2][4];
#pragma unroll
    for (int m = 0; m < 2; ++m)
#pragma unroll
        for (int nt = 0; nt < 4; ++nt) { s[m][nt] = 0.f; qs[m][nt] = 0.f; }

    int2  eA = {0, 0}, eB = {0, 0};
    u32x4 pA = (u32x4){0, 0, 0, 0}, pB = (u32x4){0, 0, 0, 0};
    f32x4 pre[12];

    int g = wglob;
    // prologue: eidx/perm for g and g+S, z gathers for g
    eA = *(const int2*)&eidx[2 * (g * 16 + r)];
    if (do_store) pA = *(const u32x4*)&perm[g * 16 + q * 4];
    if (NG >= 2) {
        eB = *(const int2*)&eidx[2 * ((g + GSTRIDE) * 16 + r)];
        if (do_store) pB = *(const u32x4*)&perm[(g + GSTRIDE) * 16 + q * 4];
    }
    {
        const float* pd = atom  + (size_t)eA.y * 64;      // dst segment
        const float* ps = atom  + (size_t)eA.x * 64;      // src segment
        const float* pe = edgef + ((size_t)g * 16 + r) * 64;
#pragma unroll
        for (int ks = 0; ks < 6; ++ks) {
            const float* sp = (ks < 2) ? pd : (ks < 4) ? ps : pe;
            const int col = (ks & 1) * 32 + q * 8;
            pre[2 * ks]     = *(const f32x4*)(sp + col);
            pre[2 * ks + 1] = *(const f32x4*)(sp + col + 4);
        }
    }

    for (int i = 0; i < NG; ++i, g += GSTRIDE) {
        // convert this group's z to bf16 fragments (waits on pre loads)
        bf16x8 a[6];
#pragma unroll
        for (int ks = 0; ks < 6; ++ks) {
            union { u16x8 u; bf16x8 b; } t;
#pragma unroll
            for (int j = 0; j < 4; ++j) {
                t.u[j]     = f2bf(pre[2 * ks][j]);
                t.u[4 + j] = f2bf(pre[2 * ks + 1][j]);
            }
            a[ks] = t.b;
        }

        // issue z gathers for group i+1 (eidx already resident in eB)
        if (i + 1 < NG) {
            const int gn = g + GSTRIDE;
            const float* pd = atom  + (size_t)eB.y * 64;
            const float* ps = atom  + (size_t)eB.x * 64;
            const float* pe = edgef + ((size_t)gn * 16 + r) * 64;
#pragma unroll
            for (int ks = 0; ks < 6; ++ks) {
                const float* sp = (ks < 2) ? pd : (ks < 4) ? ps : pe;
                const int col = (ks & 1) * 32 + q * 8;
                pre[2 * ks]     = *(const f32x4*)(sp + col);
                pre[2 * ks + 1] = *(const f32x4*)(sp + col + 4);
            }
        }
        // prefetch eidx/perm for group i+2
        int2  eC = {0, 0};
        u32x4 pC = (u32x4){0, 0, 0, 0};
        if (i + 2 < NG) {
            const int g2 = g + 2 * GSTRIDE;
            eC = *(const int2*)&eidx[2 * (g2 * 16 + r)];
            if (do_store) pC = *(const u32x4*)&perm[g2 * 16 + q * 4];
        }

        // dual GEMM: 48 MFMAs, B fragments streamed from LDS
        f32x4 acc[2][4];
#pragma unroll
        for (int m = 0; m < 2; ++m)
#pragma unroll
            for (int nt = 0; nt < 4; ++nt)
                acc[m][nt] = (f32x4){0.f, 0.f, 0.f, 0.f};
#pragma unroll
        for (int ks = 0; ks < 6; ++ks)
#pragma unroll
            for (int m = 0; m < 2; ++m)
#pragma unroll
                for (int nt = 0; nt < 4; ++nt) {
                    bf16x8 b = *(const bf16x8*)&Wl[
                        (m * 64 + nt * 16 + r) * WLSTRIDE + ks * 32 + q * 8];
                    acc[m][nt] = __builtin_amdgcn_mfma_f32_16x16x32_bf16(
                        a[ks], b, acc[m][nt], 0, 0, 0);
                }

        // stats + permuted packed store
#pragma unroll
        for (int nt = 0; nt < 4; ++nt) {
            const int c = nt * 16 + r;
#pragma unroll
            for (int rr = 0; rr < 4; ++rr) {
                float vc = acc[0][nt][rr], vf = acc[1][nt][rr];
                s[0][nt] += vc; qs[0][nt] += vc * vc;
                s[1][nt] += vf; qs[1][nt] += vf * vf;
                if (do_store) {
                    const unsigned pos = pA[rr];   // edge = g*16 + q*4 + rr
                    unsigned pack = (unsigned)f2bf(vc) | ((unsigned)f2bf(vf) << 16);
                    ws_pre[(size_t)pos * 64 + c] = pack;
                }
            }
        }

        eA = eB; eB = eC; pA = pB; pB = pC;
    }

    // block-level stat reduction
    float* slot = stat_partial + (size_t)(blockIdx.x & (STAT_SLOTS - 1)) * 256;
#pragma unroll
    for (int m = 0; m < 2; ++m)
#pragma unroll
        for (int nt = 0; nt < 4; ++nt) {
            float sv = s[m][nt], qv = qs[m][nt];
            sv += __shfl_xor(sv, 16, 64); sv += __shfl_xor(sv, 32, 64);
            qv += __shfl_xor(qv, 16, 64); qv += __shfl_xor(qv, 32, 64);
            if (lane < 16) {
                int c = nt * 16 + lane;
                atomicAdd(slot + m * 128 + c, sv);
                atomicAdd(slot + m * 128 + 64 + c, qv);
            }
        }
}

// ---------------------------------------------------------------------------
// Gather helpers (fallback path only)
// ---------------------------------------------------------------------------
__device__ __forceinline__ void gather_issue(
    const float* __restrict__ atom, const float* __restrict__ edgef,
    const int* __restrict__ eidx, int tilebase, int tid, f32x4* v)
{
    const int er = tid >> 4, f4 = tid & 15;
#pragma unroll
    for (int it = 0; it < 12; ++it) {
        const int seg = it >> 2;
        const int e   = (it & 3) * 16 + er;
        const float* srcp;
        if (seg == 0)      srcp = atom  + (size_t)eidx[2 * (tilebase + e) + 1] * 64;
        else if (seg == 1) srcp = atom  + (size_t)eidx[2 * (tilebase + e)] * 64;
        else               srcp = edgef + (size_t)(tilebase + e) * 64;
        v[it] = *(const f32x4*)(srcp + f4 * 4);
    }
}

__device__ __forceinline__ void gather_commit(const f32x4* v, ushort* zl, int tid)
{
    const int er = tid >> 4, f4 = tid & 15;
#pragma unroll
    for (int it = 0; it < 12; ++it) {
        const int seg = it >> 2;
        const int e   = (it & 3) * 16 + er;
        u16x4 b;
        b.x = f2bf(v[it].x); b.y = f2bf(v[it].y);
        b.z = f2bf(v[it].z); b.w = f2bf(v[it].w);
        *(u16x4*)&zl[e * ZSTRIDE + seg * 64 + f4 * 4] = b;
    }
}

// ---------------------------------------------------------------------------
// Fold BN into per-column scale/shift.
// params: [0..63]=scale_c [64..127]=scale_f [128..191]=shift_c [192..255]=shift_f
// ---------------------------------------------------------------------------
__global__ void finalize_stats(const float* __restrict__ stat_partial,
                               const float* __restrict__ gc, const float* __restrict__ btc,
                               const float* __restrict__ gf, const float* __restrict__ btf,
                               float* __restrict__ params)
{
    int t = threadIdx.x;            // 0..127
    bool isf = t >= 64;
    int j = t & 63;
    float s = 0.f, q = 0.f;
    for (int slot = 0; slot < STAT_SLOTS; slot++) {
        const float* sp = stat_partial + (size_t)slot * 256 + (isf ? 128 : 0);
        s += sp[j];
        q += sp[64 + j];
    }
    float mean = s / (float)N_EDGES;
    float var  = q / (float)N_EDGES - mean * mean;
    float inv  = rsqrtf(var + BN_EPS);
    float gamma = isf ? gf[j] : gc[j];
    float beta  = isf ? btf[j] : btc[j];
    float scale = gamma * inv;
    float shift = beta - mean * scale;
    params[t]       = scale;
    params[128 + t] = shift;
}

__global__ __launch_bounds__(256) void convert_weights(
    const float* __restrict__ Wc, const float* __restrict__ Wf,
    ushort* __restrict__ Wb)
{
    int i = blockIdx.x * 256 + threadIdx.x;
    float v = (i < 64 * KDIM) ? Wc[i] : Wf[i - 64 * KDIM];
    Wb[i] = f2bf(v);
}

// ---------------------------------------------------------------------------
// CSR-slot assignment: histogram -> 2-level exclusive scan -> cursors ->
// perm[e] = slot (coalesced write; no scattered csr array).
// ---------------------------------------------------------------------------
__global__ __launch_bounds__(256) void hist_dst(const int* __restrict__ eidx,
                                                unsigned* __restrict__ counts)
{
    int e = blockIdx.x * 256 + threadIdx.x;          // 3125 blocks
    atomicAdd(&counts[eidx[2 * e + 1]], 1u);
}

__global__ __launch_bounds__(256) void scan_a(const unsigned* __restrict__ counts,
                                              unsigned* __restrict__ row_start,
                                              unsigned* __restrict__ blksum)
{
    __shared__ unsigned sh[256];
    const int tid = threadIdx.x;
    const int i = blockIdx.x * 256 + tid;
    unsigned v = (i < N_ATOMS) ? counts[i] : 0u;
    sh[tid] = v;
    __syncthreads();
    for (int off = 1; off < 256; off <<= 1) {
        unsigned t = (tid >= off) ? sh[tid - off] : 0u;
        __syncthreads();
        sh[tid] += t;
        __syncthreads();
    }
    if (i < N_ATOMS) row_start[i] = sh[tid] - v;     // exclusive
    if (tid == 255) blksum[blockIdx.x] = sh[tid];
}

__global__ void scan_b(unsigned* __restrict__ blksum)   // 1 block
{
    __shared__ unsigned sh[256];
    const int tid = threadIdx.x;
    unsigned v = (tid < NSCANBLK) ? blksum[tid] : 0u;
    sh[tid] = v;
    __syncthreads();
    for (int off = 1; off < 256; off <<= 1) {
        unsigned t = (tid >= off) ? sh[tid - off] : 0u;
        __syncthreads();
        sh[tid] += t;
        __syncthreads();
    }
    if (tid < NSCANBLK) blksum[tid] = sh[tid] - v;   // exclusive
}

__global__ __launch_bounds__(256) void init_cursor(unsigned* __restrict__ row_start,
                                                   const unsigned* __restrict__ blksum,
                                                   unsigned* __restrict__ cursors)
{
    int i = blockIdx.x * 256 + threadIdx.x;
    if (i < N_ATOMS) {
        unsigned base = row_start[i] + blksum[i >> 8];
        row_start[i] = base;
        cursors[i]   = base;
    }
    if (i == 0) row_start[N_ATOMS] = N_EDGES;
}

__global__ __launch_bounds__(256) void fill_perm(const int* __restrict__ eidx,
                                                 unsigned* __restrict__ cursors,
                                                 unsigned* __restrict__ perm)
{
    int e = blockIdx.x * 256 + threadIdx.x;
    int d = eidx[2 * e + 1];
    perm[e] = atomicAdd(&cursors[d], 1u);   // coalesced perm write
}

// ---------------------------------------------------------------------------
// Pass 3: streaming gather-reduce. ws_pre rows are already in CSR order, so
// each wave (one atom, lane = column) reads a CONTIGUOUS run of 256B rows.
// One plain store per atom; no atomics, no index indirection.
// ---------------------------------------------------------------------------
__global__ __launch_bounds__(256) void bn_act_reduce(
    const unsigned* __restrict__ ws_pre, const unsigned* __restrict__ row_start,
    const float* __restrict__ atom, const float* __restrict__ params,
    float* __restrict__ out)
{
    const int lane = threadIdx.x & 63;
    const int a    = blockIdx.x * 4 + (threadIdx.x >> 6);

    const float sc_c = params[lane],      sh_c = params[128 + lane];
    const float sc_f = params[64 + lane], sh_f = params[192 + lane];

    const unsigned jb = row_start[a];
    const unsigned n  = row_start[a + 1] - jb;
    const unsigned* base = ws_pre + (size_t)jb * 64 + lane;

    float acc = 0.f;
    unsigned k = 0;
    for (; k + 8 <= n; k += 8) {
        unsigned p[8];
#pragma unroll
        for (int u = 0; u < 8; ++u) p[u] = base[(size_t)(k + u) * 64];
#pragma unroll
        for (int u = 0; u < 8; ++u) acc += msgf(p[u], sc_c, sh_c, sc_f, sh_f);
    }
    for (; k < n; ++k) acc += msgf(base[(size_t)k * 64], sc_c, sh_c, sc_f, sh_f);

    out[(size_t)a * 64 + lane] = atom[(size_t)a * 64 + lane] + acc;
}

// ---------------------------------------------------------------------------
// Fallback path (ws too small): recompute GEMM + atomic scatter (no ws_pre).
// ---------------------------------------------------------------------------
__global__ __launch_bounds__(256) void copy_out(const f32x4* __restrict__ src,
                                                f32x4* __restrict__ dst)
{
    int i = blockIdx.x * blockDim.x + threadIdx.x;
    dst[i] = src[i];
}

__global__ __launch_bounds__(256) void apply_scatter_fb(
    const float* __restrict__ atom, const float* __restrict__ edgef,
    const ushort* __restrict__ Wb, const int* __restrict__ eidx,
    const float* __restrict__ params, float* __restrict__ out)
{
    __shared__ __align__(16) ushort zl[TILE_E * ZSTRIDE];
    const int tid  = threadIdx.x;
    const int lane = tid & 63, wave = tid >> 6;
    const int ch = wave >> 1, rp = wave & 1;
    const int row = lane & 15, quad = lane >> 4;

    bf16x8 bfr[2][2][6];
#pragma unroll
    for (int m = 0; m < 2; ++m)
#pragma unroll
        for (int nt = 0; nt < 2; ++nt)
#pragma unroll
            for (int ks = 0; ks < 6; ++ks)
                bfr[m][nt][ks] = *(const bf16x8*)&Wb[
                    (size_t)(m * 64 + ch * 32 + nt * 16 + row) * KDIM + ks * 32 + quad * 8];

    float scc[2], shc[2], scf[2], shf[2];
#pragma unroll
    for (int nt = 0; nt < 2; ++nt) {
        int c = ch * 32 + nt * 16 + row;
        scc[nt] = params[c];        shc[nt] = params[128 + c];
        scf[nt] = params[64 + c];   shf[nt] = params[192 + c];
    }

    const int t0 = blockIdx.x * TPB;
    for (int tt = 0; tt < TPB; ++tt) {
        const int tilebase = (t0 + tt) * TILE_E;
        f32x4 pre[12];
        gather_issue(atom, edgef, eidx, tilebase, tid, pre);
        __syncthreads();
        gather_commit(pre, zl, tid);
        __syncthreads();
#pragma unroll
        for (int ett = 0; ett < 2; ++ett) {
            const ushort* zb = zl + ((2 * rp + ett) * 16 + row) * ZSTRIDE;
            bf16x8 a[6];
#pragma unroll
            for (int ks = 0; ks < 6; ++ks)
                a[ks] = *(const bf16x8*)&zb[ks * 32 + quad * 8];
            f32x4 acc[2][2];
#pragma unroll
            for (int m = 0; m < 2; ++m)
#pragma unroll
                for (int nt = 0; nt < 2; ++nt)
                    acc[m][nt] = (f32x4){0.f, 0.f, 0.f, 0.f};
#pragma unroll
            for (int ks = 0; ks < 6; ++ks)
#pragma unroll
                for (int m = 0; m < 2; ++m)
#pragma unroll
                    for (int nt = 0; nt < 2; ++nt)
                        acc[m][nt] = __builtin_amdgcn_mfma_f32_16x16x32_bf16(
                            a[ks], bfr[m][nt][ks], acc[m][nt], 0, 0, 0);
#pragma unroll
            for (int nt = 0; nt < 2; ++nt) {
                int c = ch * 32 + nt * 16 + row;
#pragma unroll
                for (int r = 0; r < 4; ++r) {
                    float pc = fmaf(acc[0][nt][r], scc[nt], shc[nt]);
                    float pf = fmaf(acc[1][nt][r], scf[nt], shf[nt]);
                    float sp = fmaxf(pc, 0.f) + __logf(1.f + __expf(-fabsf(pc)));
                    float sg = 1.f / (1.f + __expf(-pf));
                    int eloc = (2 * rp + ett) * 16 + quad * 4 + r;
                    int d = eidx[2 * (tilebase + eloc) + 1];
                    atomicAdd(out + (size_t)d * 64 + c, sp * sg);
                }
            }
        }
    }
}

// ---------------------------------------------------------------------------
extern "C" void kernel_launch(void* const* d_in, const int* in_sizes, int n_in,
                              void* d_out, int out_size, void* d_ws, size_t ws_size,
                              hipStream_t stream)
{
    const float* atom  = (const float*)d_in[0];
    const float* edgef = (const float*)d_in[1];
    const float* Wf    = (const float*)d_in[2];
    const float* gf    = (const float*)d_in[4];
    const float* btf   = (const float*)d_in[5];
    const float* Wc    = (const float*)d_in[6];
    const float* gc    = (const float*)d_in[8];
    const float* btc   = (const float*)d_in[9];
    const int*   eidx  = (const int*)d_in[10];
    float* out = (float*)d_out;

    // workspace layout (ws_pre first keeps everything 16B-aligned)
    unsigned* ws_pre       = (unsigned*)d_ws;                          // N_EDGES*64
    float*    stat_partial = (float*)(ws_pre + (size_t)N_EDGES * 64);  // 8192 f32
    float*    params       = stat_partial + STAT_SLOTS * 256;          // 256 f32
    ushort*   Wb           = (ushort*)(params + 256);                  // 24576 bf16
    unsigned* counts       = (unsigned*)(Wb + 2 * 64 * KDIM);          // 50000
    unsigned* row_start    = counts + N_ATOMS;                         // 50001
    unsigned* blksum       = row_start + N_ATOMS + 1;                  // 256
    unsigned* cursors      = blksum + 256;                             // 50000
    unsigned* perm         = cursors + N_ATOMS;                        // 800000

    const size_t need_full = (size_t)((char*)(perm + N_EDGES) - (char*)d_ws);
    const int full = (ws_size >= need_full) ? 1 : 0;

    (void)hipMemsetAsync(stat_partial, 0, STAT_SLOTS * 256 * sizeof(float), stream);
    convert_weights<<<(2 * 64 * KDIM) / 256, 256, 0, stream>>>(Wc, Wf, Wb);

    if (full) {
        (void)hipMemsetAsync(counts, 0, N_ATOMS * sizeof(unsigned), stream);
        hist_dst<<<N_EDGES / 256, 256, 0, stream>>>(eidx, counts);
        scan_a<<<NSCANBLK, 256, 0, stream>>>(counts, row_start, blksum);
        scan_b<<<1, 256, 0, stream>>>(blksum);
        init_cursor<<<NSCANBLK, 256, 0, stream>>>(row_start, blksum, cursors);
        fill_perm<<<N_EDGES / 256, 256, 0, stream>>>(eidx, cursors, perm);
        gemm_stats_direct<<<GRID_DIR, 256, 0, stream>>>(atom, edgef, Wb, eidx, perm,
                                                        stat_partial, ws_pre, 1);
        finalize_stats<<<1, 128, 0, stream>>>(stat_partial, gc, btc, gf, btf, params);
        bn_act_reduce<<<N_ATOMS / 4, 256, 0, stream>>>(ws_pre, row_start,
                                                       atom, params, out);
    } else {
        gemm_stats_direct<<<GRID_DIR, 256, 0, stream>>>(atom, edgef, Wb, eidx,
                                                        (const unsigned*)counts /*unused*/,
                                                        stat_partial, ws_pre, 0);
        finalize_stats<<<1, 128, 0, stream>>>(stat_partial, gc, btc, gf, btf, params);
        copy_out<<<(N_ATOMS * 64 / 4) / 256, 256, 0, stream>>>(
            (const f32x4*)atom, (f32x4*)out);
        apply_scatter_fb<<<GRID1, 256, 0, stream>>>(atom, edgef, Wb, eidx,
                                                    params, out);
    }
}

// Round 2
// 840.323 us; speedup vs baseline: 1.0288x; 1.0288x over previous
//
#include <hip/hip_runtime.h>
#include <hip/hip_bf16.h>
#include <math.h>

// Problem constants
#define N_ATOMS   50000
#define N_EDGES   800000
#define KDIM      192
#define BN_EPS    1e-5f

#define TILE_E     64
#define TPB        5                       // tiles per block (pass 1)
#define NTILES     (N_EDGES / TILE_E)      // 12500
#define GRID1      (NTILES / TPB)          // 2500
#define STAT_SLOTS 32
#define ZSTRIDE    200   // bf16 elems per FULL z row (fallback kernel LDS)
#define ZAST       136   // bf16 elems per 2-seg z row (main kernel: 128 + 8 pad)
#define NSCANBLK   ((N_ATOMS + 255) / 256) // 196

typedef __attribute__((ext_vector_type(8))) __bf16 bf16x8;
typedef __attribute__((ext_vector_type(4))) float  f32x4;
typedef __attribute__((ext_vector_type(4))) unsigned short u16x4;
typedef __attribute__((ext_vector_type(8))) unsigned short u16x8;

__device__ __forceinline__ ushort f2bf(float f) {
    union { float f; unsigned u; } v; v.f = f;
    unsigned u = v.u;
    return (ushort)((u + 0x7FFFu + ((u >> 16) & 1u)) >> 16);
}
__device__ __forceinline__ float bf2f(unsigned hi16) {
    union { unsigned u; float f; } v; v.u = hi16 << 16; return v.f;
}
// BN + sigmoid*softplus message from packed (core | filter<<16) bf16 pair
__device__ __forceinline__ float msgf(unsigned pv, float sc_c, float sh_c,
                                      float sc_f, float sh_f) {
    float pc = fmaf(bf2f(pv & 0xFFFFu), sc_c, sh_c);
    float pf = fmaf(bf2f(pv >> 16),     sc_f, sh_f);
    float sp = fmaxf(pc, 0.f) + __logf(1.f + __expf(-fabsf(pc)));
    float sg = 1.f / (1.f + __expf(-pf));
    return sp * sg;
}

// ---------------------------------------------------------------------------
// Gather split (ATOM segments only for main kernel): issue (global->regs) /
// commit (bf16 convert -> LDS). 16 lanes read one 256B atom row contiguously
// (4 whole rows per instruction) -- this coalescing is why FETCH stays low.
// eidx read directly from global (16 threads/edge share -> L1 broadcast).
// ---------------------------------------------------------------------------
__device__ __forceinline__ void gather_issue_a(
    const float* __restrict__ atom, const int* __restrict__ eidx,
    int tilebase, int tid, f32x4* v)
{
    const int er = tid >> 4, f4 = tid & 15;
#pragma unroll
    for (int it = 0; it < 8; ++it) {
        const int seg = it >> 2;                 // 0=dst, 1=src
        const int e   = (it & 3) * 16 + er;
        const float* srcp =
            atom + (size_t)eidx[2 * (tilebase + e) + (seg == 0 ? 1 : 0)] * 64;
        v[it] = *(const f32x4*)(srcp + f4 * 4);
    }
}

__device__ __forceinline__ void gather_commit_a(const f32x4* v, ushort* zl, int tid)
{
    const int er = tid >> 4, f4 = tid & 15;
#pragma unroll
    for (int it = 0; it < 8; ++it) {
        const int seg = it >> 2;
        const int e   = (it & 3) * 16 + er;
        u16x4 b;
        b.x = f2bf(v[it].x); b.y = f2bf(v[it].y);
        b.z = f2bf(v[it].z); b.w = f2bf(v[it].w);
        *(u16x4*)&zl[e * ZAST + seg * 64 + f4 * 4] = b;
    }
}

// Full-z gather helpers (fallback kernel only)
__device__ __forceinline__ void gather_issue(
    const float* __restrict__ atom, const float* __restrict__ edgef,
    const int* __restrict__ eidx, int tilebase, int tid, f32x4* v)
{
    const int er = tid >> 4, f4 = tid & 15;
#pragma unroll
    for (int it = 0; it < 12; ++it) {
        const int seg = it >> 2;
        const int e   = (it & 3) * 16 + er;
        const float* srcp;
        if (seg == 0)      srcp = atom  + (size_t)eidx[2 * (tilebase + e) + 1] * 64;
        else if (seg == 1) srcp = atom  + (size_t)eidx[2 * (tilebase + e)] * 64;
        else               srcp = edgef + (size_t)(tilebase + e) * 64;
        v[it] = *(const f32x4*)(srcp + f4 * 4);
    }
}

__device__ __forceinline__ void gather_commit(const f32x4* v, ushort* zl, int tid)
{
    const int er = tid >> 4, f4 = tid & 15;
#pragma unroll
    for (int it = 0; it < 12; ++it) {
        const int seg = it >> 2;
        const int e   = (it & 3) * 16 + er;
        u16x4 b;
        b.x = f2bf(v[it].x); b.y = f2bf(v[it].y);
        b.z = f2bf(v[it].z); b.w = f2bf(v[it].w);
        *(u16x4*)&zl[e * ZSTRIDE + seg * 64 + f4 * 4] = b;
    }
}

// ---------------------------------------------------------------------------
// Pass 1: prefetch-double-buffered atom gather + MFMA dual-GEMM + col sum/sumsq.
// Edge-feature A-fragments (ks=4,5) load DIRECTLY from global in fragment
// layout (edgef rows are contiguous by edge id -> coalesced, no LDS needed),
// shrinking LDS to 36.1KB -> 4 blocks/CU (was 3).
// Pre-act rows stored PERMUTED to CSR slots (perm[e]); bias dropped (BN).
// One __syncthreads per tile: commit(t) | sync | issue(t+1) | MFMA(t)+store.
// ---------------------------------------------------------------------------
__global__ __launch_bounds__(256, 4) void gemm_stats_store(
    const float* __restrict__ atom, const float* __restrict__ edgef,
    const ushort* __restrict__ Wb, const int* __restrict__ eidx,
    const unsigned* __restrict__ perm,
    float* __restrict__ stat_partial, unsigned* __restrict__ ws_pre,
    int do_store)
{
    __shared__ __align__(16) ushort zbuf[2][TILE_E * ZAST]; // 2x17.0KB
    __shared__ unsigned perml[TPB * TILE_E];                // 1.25KB
    const int tid  = threadIdx.x;
    const int lane = tid & 63, wave = tid >> 6;
    const int ch = wave >> 1, rp = wave & 1;
    const int row = lane & 15, quad = lane >> 4;

    const int t0 = blockIdx.x * TPB;
    for (int i = tid; i < TPB * TILE_E; i += 256)
        perml[i] = perm[t0 * TILE_E + i];

    bf16x8 bfr[2][2][6];
#pragma unroll
    for (int m = 0; m < 2; ++m)
#pragma unroll
        for (int nt = 0; nt < 2; ++nt)
#pragma unroll
            for (int ks = 0; ks < 6; ++ks)
                bfr[m][nt][ks] = *(const bf16x8*)&Wb[
                    (size_t)(m * 64 + ch * 32 + nt * 16 + row) * KDIM + ks * 32 + quad * 8];

    float s[2][2] = {{0.f, 0.f}, {0.f, 0.f}};
    float q[2][2] = {{0.f, 0.f}, {0.f, 0.f}};

    f32x4 pre[8];
    gather_issue_a(atom, eidx, t0 * TILE_E, tid, pre);

    for (int tt = 0; tt < TPB; ++tt) {
        ushort* zl = zbuf[tt & 1];
        gather_commit_a(pre, zl, tid);
        __syncthreads();   // zl visible; also protects buffer reuse
        if (tt + 1 < TPB)
            gather_issue_a(atom, eidx, (t0 + tt + 1) * TILE_E, tid, pre);

#pragma unroll
        for (int ett = 0; ett < 2; ++ett) {
            // direct edge-feature fragment loads (z cols 128..191)
            const size_t ebase =
                (size_t)((t0 + tt) * TILE_E + (2 * rp + ett) * 16 + row) * 64;
            f32x4 ef0 = *(const f32x4*)&edgef[ebase + quad * 8];
            f32x4 ef1 = *(const f32x4*)&edgef[ebase + quad * 8 + 4];
            f32x4 ef2 = *(const f32x4*)&edgef[ebase + 32 + quad * 8];
            f32x4 ef3 = *(const f32x4*)&edgef[ebase + 32 + quad * 8 + 4];

            const ushort* zb = zl + ((2 * rp + ett) * 16 + row) * ZAST;
            bf16x8 a[6];
#pragma unroll
            for (int ks = 0; ks < 4; ++ks)
                a[ks] = *(const bf16x8*)&zb[ks * 32 + quad * 8];
            {
                union { u16x8 u; bf16x8 b; } t4, t5;
#pragma unroll
                for (int j = 0; j < 4; ++j) {
                    t4.u[j]     = f2bf(ef0[j]);
                    t4.u[4 + j] = f2bf(ef1[j]);
                    t5.u[j]     = f2bf(ef2[j]);
                    t5.u[4 + j] = f2bf(ef3[j]);
                }
                a[4] = t4.b; a[5] = t5.b;
            }

            f32x4 acc[2][2];
#pragma unroll
            for (int m = 0; m < 2; ++m)
#pragma unroll
                for (int nt = 0; nt < 2; ++nt)
                    acc[m][nt] = (f32x4){0.f, 0.f, 0.f, 0.f};
#pragma unroll
            for (int ks = 0; ks < 6; ++ks)
#pragma unroll
                for (int m = 0; m < 2; ++m)
#pragma unroll
                    for (int nt = 0; nt < 2; ++nt)
                        acc[m][nt] = __builtin_amdgcn_mfma_f32_16x16x32_bf16(
                            a[ks], bfr[m][nt][ks], acc[m][nt], 0, 0, 0);
#pragma unroll
            for (int nt = 0; nt < 2; ++nt) {
                const int c = ch * 32 + nt * 16 + row;
#pragma unroll
                for (int r = 0; r < 4; ++r) {
                    float vc = acc[0][nt][r], vf = acc[1][nt][r];
                    s[0][nt] += vc; q[0][nt] += vc * vc;
                    s[1][nt] += vf; q[1][nt] += vf * vf;
                    if (do_store) {
                        const int eloc = (2 * rp + ett) * 16 + quad * 4 + r;
                        const unsigned pos = perml[tt * TILE_E + eloc];
                        unsigned pack = (unsigned)f2bf(vc) | ((unsigned)f2bf(vf) << 16);
                        ws_pre[(size_t)pos * 64 + c] = pack;  // plain store: L2 merges
                    }
                }
            }
        }
    }

    float* slot = stat_partial + (size_t)(blockIdx.x & (STAT_SLOTS - 1)) * 256;
#pragma unroll
    for (int m = 0; m < 2; ++m)
#pragma unroll
        for (int nt = 0; nt < 2; ++nt) {
            float sv = s[m][nt], qv = q[m][nt];
            sv += __shfl_xor(sv, 16, 64); sv += __shfl_xor(sv, 32, 64);
            qv += __shfl_xor(qv, 16, 64); qv += __shfl_xor(qv, 32, 64);
            if (lane < 16) {
                int c = ch * 32 + nt * 16 + lane;
                atomicAdd(slot + m * 128 + c, sv);
                atomicAdd(slot + m * 128 + 64 + c, qv);
            }
        }
}

// ---------------------------------------------------------------------------
// Fold BN into per-column scale/shift.
// params: [0..63]=scale_c [64..127]=scale_f [128..191]=shift_c [192..255]=shift_f
// ---------------------------------------------------------------------------
__global__ void finalize_stats(const float* __restrict__ stat_partial,
                               const float* __restrict__ gc, const float* __restrict__ btc,
                               const float* __restrict__ gf, const float* __restrict__ btf,
                               float* __restrict__ params)
{
    int t = threadIdx.x;            // 0..127
    bool isf = t >= 64;
    int j = t & 63;
    float s = 0.f, q = 0.f;
    for (int slot = 0; slot < STAT_SLOTS; slot++) {
        const float* sp = stat_partial + (size_t)slot * 256 + (isf ? 128 : 0);
        s += sp[j];
        q += sp[64 + j];
    }
    float mean = s / (float)N_EDGES;
    float var  = q / (float)N_EDGES - mean * mean;
    float inv  = rsqrtf(var + BN_EPS);
    float gamma = isf ? gf[j] : gc[j];
    float beta  = isf ? btf[j] : btc[j];
    float scale = gamma * inv;
    float shift = beta - mean * scale;
    params[t]       = scale;
    params[128 + t] = shift;
}

__global__ __launch_bounds__(256) void convert_weights(
    const float* __restrict__ Wc, const float* __restrict__ Wf,
    ushort* __restrict__ Wb)
{
    int i = blockIdx.x * 256 + threadIdx.x;
    float v = (i < 64 * KDIM) ? Wc[i] : Wf[i - 64 * KDIM];
    Wb[i] = f2bf(v);
}

// ---------------------------------------------------------------------------
// CSR-slot assignment: histogram -> 2-level exclusive scan -> cursors ->
// perm[e] = slot (coalesced write; no scattered csr array).
// ---------------------------------------------------------------------------
__global__ __launch_bounds__(256) void hist_dst(const int* __restrict__ eidx,
                                                unsigned* __restrict__ counts)
{
    int e = blockIdx.x * 256 + threadIdx.x;          // 3125 blocks
    atomicAdd(&counts[eidx[2 * e + 1]], 1u);
}

__global__ __launch_bounds__(256) void scan_a(const unsigned* __restrict__ counts,
                                              unsigned* __restrict__ row_start,
                                              unsigned* __restrict__ blksum)
{
    __shared__ unsigned sh[256];
    const int tid = threadIdx.x;
    const int i = blockIdx.x * 256 + tid;
    unsigned v = (i < N_ATOMS) ? counts[i] : 0u;
    sh[tid] = v;
    __syncthreads();
    for (int off = 1; off < 256; off <<= 1) {
        unsigned t = (tid >= off) ? sh[tid - off] : 0u;
        __syncthreads();
        sh[tid] += t;
        __syncthreads();
    }
    if (i < N_ATOMS) row_start[i] = sh[tid] - v;     // exclusive
    if (tid == 255) blksum[blockIdx.x] = sh[tid];
}

__global__ void scan_b(unsigned* __restrict__ blksum)   // 1 block
{
    __shared__ unsigned sh[256];
    const int tid = threadIdx.x;
    unsigned v = (tid < NSCANBLK) ? blksum[tid] : 0u;
    sh[tid] = v;
    __syncthreads();
    for (int off = 1; off < 256; off <<= 1) {
        unsigned t = (tid >= off) ? sh[tid - off] : 0u;
        __syncthreads();
        sh[tid] += t;
        __syncthreads();
    }
    if (tid < NSCANBLK) blksum[tid] = sh[tid] - v;   // exclusive
}

__global__ __launch_bounds__(256) void init_cursor(unsigned* __restrict__ row_start,
                                                   const unsigned* __restrict__ blksum,
                                                   unsigned* __restrict__ cursors)
{
    int i = blockIdx.x * 256 + threadIdx.x;
    if (i < N_ATOMS) {
        unsigned base = row_start[i] + blksum[i >> 8];
        row_start[i] = base;
        cursors[i]   = base;
    }
    if (i == 0) row_start[N_ATOMS] = N_EDGES;
}

__global__ __launch_bounds__(256) void fill_perm(const int* __restrict__ eidx,
                                                 unsigned* __restrict__ cursors,
                                                 unsigned* __restrict__ perm)
{
    int e = blockIdx.x * 256 + threadIdx.x;
    int d = eidx[2 * e + 1];
    perm[e] = atomicAdd(&cursors[d], 1u);   // coalesced perm write
}

// ---------------------------------------------------------------------------
// Pass 3: streaming gather-reduce. ws_pre rows are already in CSR order, so
// each wave (one atom, lane = column) reads a CONTIGUOUS run of 256B rows.
// One plain store per atom; no atomics, no index indirection.
// ---------------------------------------------------------------------------
__global__ __launch_bounds__(256) void bn_act_reduce(
    const unsigned* __restrict__ ws_pre, const unsigned* __restrict__ row_start,
    const float* __restrict__ atom, const float* __restrict__ params,
    float* __restrict__ out)
{
    const int lane = threadIdx.x & 63;
    const int a    = blockIdx.x * 4 + (threadIdx.x >> 6);

    const float sc_c = params[lane],      sh_c = params[128 + lane];
    const float sc_f = params[64 + lane], sh_f = params[192 + lane];

    const unsigned jb = row_start[a];
    const unsigned n  = row_start[a + 1] - jb;
    const unsigned* base = ws_pre + (size_t)jb * 64 + lane;

    float acc = 0.f;
    unsigned k = 0;
    for (; k + 8 <= n; k += 8) {
        unsigned p[8];
#pragma unroll
        for (int u = 0; u < 8; ++u) p[u] = base[(size_t)(k + u) * 64];
#pragma unroll
        for (int u = 0; u < 8; ++u) acc += msgf(p[u], sc_c, sh_c, sc_f, sh_f);
    }
    for (; k < n; ++k) acc += msgf(base[(size_t)k * 64], sc_c, sh_c, sc_f, sh_f);

    out[(size_t)a * 64 + lane] = atom[(size_t)a * 64 + lane] + acc;
}

// ---------------------------------------------------------------------------
// Fallback path (ws too small): recompute GEMM + atomic scatter (no ws_pre).
// ---------------------------------------------------------------------------
__global__ __launch_bounds__(256) void copy_out(const f32x4* __restrict__ src,
                                                f32x4* __restrict__ dst)
{
    int i = blockIdx.x * blockDim.x + threadIdx.x;
    dst[i] = src[i];
}

__global__ __launch_bounds__(256) void apply_scatter_fb(
    const float* __restrict__ atom, const float* __restrict__ edgef,
    const ushort* __restrict__ Wb, const int* __restrict__ eidx,
    const float* __restrict__ params, float* __restrict__ out)
{
    __shared__ __align__(16) ushort zl[TILE_E * ZSTRIDE];
    const int tid  = threadIdx.x;
    const int lane = tid & 63, wave = tid >> 6;
    const int ch = wave >> 1, rp = wave & 1;
    const int row = lane & 15, quad = lane >> 4;

    bf16x8 bfr[2][2][6];
#pragma unroll
    for (int m = 0; m < 2; ++m)
#pragma unroll
        for (int nt = 0; nt < 2; ++nt)
#pragma unroll
            for (int ks = 0; ks < 6; ++ks)
                bfr[m][nt][ks] = *(const bf16x8*)&Wb[
                    (size_t)(m * 64 + ch * 32 + nt * 16 + row) * KDIM + ks * 32 + quad * 8];

    float scc[2], shc[2], scf[2], shf[2];
#pragma unroll
    for (int nt = 0; nt < 2; ++nt) {
        int c = ch * 32 + nt * 16 + row;
        scc[nt] = params[c];        shc[nt] = params[128 + c];
        scf[nt] = params[64 + c];   shf[nt] = params[192 + c];
    }

    const int t0 = blockIdx.x * TPB;
    for (int tt = 0; tt < TPB; ++tt) {
        const int tilebase = (t0 + tt) * TILE_E;
        f32x4 pre[12];
        gather_issue(atom, edgef, eidx, tilebase, tid, pre);
        __syncthreads();
        gather_commit(pre, zl, tid);
        __syncthreads();
#pragma unroll
        for (int ett = 0; ett < 2; ++ett) {
            const ushort* zb = zl + ((2 * rp + ett) * 16 + row) * ZSTRIDE;
            bf16x8 a[6];
#pragma unroll
            for (int ks = 0; ks < 6; ++ks)
                a[ks] = *(const bf16x8*)&zb[ks * 32 + quad * 8];
            f32x4 acc[2][2];
#pragma unroll
            for (int m = 0; m < 2; ++m)
#pragma unroll
                for (int nt = 0; nt < 2; ++nt)
                    acc[m][nt] = (f32x4){0.f, 0.f, 0.f, 0.f};
#pragma unroll
            for (int ks = 0; ks < 6; ++ks)
#pragma unroll
                for (int m = 0; m < 2; ++m)
#pragma unroll
                    for (int nt = 0; nt < 2; ++nt)
                        acc[m][nt] = __builtin_amdgcn_mfma_f32_16x16x32_bf16(
                            a[ks], bfr[m][nt][ks], acc[m][nt], 0, 0, 0);
#pragma unroll
            for (int nt = 0; nt < 2; ++nt) {
                int c = ch * 32 + nt * 16 + row;
#pragma unroll
                for (int r = 0; r < 4; ++r) {
                    float pc = fmaf(acc[0][nt][r], scc[nt], shc[nt]);
                    float pf = fmaf(acc[1][nt][r], scf[nt], shf[nt]);
                    float sp = fmaxf(pc, 0.f) + __logf(1.f + __expf(-fabsf(pc)));
                    float sg = 1.f / (1.f + __expf(-pf));
                    int eloc = (2 * rp + ett) * 16 + quad * 4 + r;
                    int d = eidx[2 * (tilebase + eloc) + 1];
                    atomicAdd(out + (size_t)d * 64 + c, sp * sg);
                }
            }
        }
    }
}

// ---------------------------------------------------------------------------
extern "C" void kernel_launch(void* const* d_in, const int* in_sizes, int n_in,
                              void* d_out, int out_size, void* d_ws, size_t ws_size,
                              hipStream_t stream)
{
    const float* atom  = (const float*)d_in[0];
    const float* edgef = (const float*)d_in[1];
    const float* Wf    = (const float*)d_in[2];
    const float* gf    = (const float*)d_in[4];
    const float* btf   = (const float*)d_in[5];
    const float* Wc    = (const float*)d_in[6];
    const float* gc    = (const float*)d_in[8];
    const float* btc   = (const float*)d_in[9];
    const int*   eidx  = (const int*)d_in[10];
    float* out = (float*)d_out;

    // workspace layout (ws_pre first keeps everything 16B-aligned)
    unsigned* ws_pre       = (unsigned*)d_ws;                          // N_EDGES*64
    float*    stat_partial = (float*)(ws_pre + (size_t)N_EDGES * 64);  // 8192 f32
    float*    params       = stat_partial + STAT_SLOTS * 256;          // 256 f32
    ushort*   Wb           = (ushort*)(params + 256);                  // 24576 bf16
    unsigned* counts       = (unsigned*)(Wb + 2 * 64 * KDIM);          // 50000
    unsigned* row_start    = counts + N_ATOMS;                         // 50001
    unsigned* blksum       = row_start + N_ATOMS + 1;                  // 256
    unsigned* cursors      = blksum + 256;                             // 50000
    unsigned* perm         = cursors + N_ATOMS;                        // 800000

    const size_t need_full = (size_t)((char*)(perm + N_EDGES) - (char*)d_ws);
    const int full = (ws_size >= need_full) ? 1 : 0;

    (void)hipMemsetAsync(stat_partial, 0, STAT_SLOTS * 256 * sizeof(float), stream);
    convert_weights<<<(2 * 64 * KDIM) / 256, 256, 0, stream>>>(Wc, Wf, Wb);

    if (full) {
        (void)hipMemsetAsync(counts, 0, N_ATOMS * sizeof(unsigned), stream);
        hist_dst<<<N_EDGES / 256, 256, 0, stream>>>(eidx, counts);
        scan_a<<<NSCANBLK, 256, 0, stream>>>(counts, row_start, blksum);
        scan_b<<<1, 256, 0, stream>>>(blksum);
        init_cursor<<<NSCANBLK, 256, 0, stream>>>(row_start, blksum, cursors);
        fill_perm<<<N_EDGES / 256, 256, 0, stream>>>(eidx, cursors, perm);
        gemm_stats_store<<<GRID1, 256, 0, stream>>>(atom, edgef, Wb, eidx, perm,
                                                    stat_partial, ws_pre, 1);
        finalize_stats<<<1, 128, 0, stream>>>(stat_partial, gc, btc, gf, btf, params);
        bn_act_reduce<<<N_ATOMS / 4, 256, 0, stream>>>(ws_pre, row_start,
                                                       atom, params, out);
    } else {
        gemm_stats_store<<<GRID1, 256, 0, stream>>>(atom, edgef, Wb, eidx,
                                                    (unsigned*)counts /*unused*/,
                                                    stat_partial, ws_pre, 0);
        finalize_stats<<<1, 128, 0, stream>>>(stat_partial, gc, btc, gf, btf, params);
        copy_out<<<(N_ATOMS * 64 / 4) / 256, 256, 0, stream>>>(
            (const f32x4*)atom, (f32x4*)out);
        apply_scatter_fb<<<GRID1, 256, 0, stream>>>(atom, edgef, Wb, eidx,
                                                    params, out);
    }
}

// Round 3
// 704.185 us; speedup vs baseline: 1.2277x; 1.1933x over previous
//
#include <hip/hip_runtime.h>
#include <hip/hip_bf16.h>
#include <math.h>

// Problem constants
#define N_ATOMS   50000
#define N_EDGES   800000
#define KDIM      192
#define BN_EPS    1e-5f

#define TILE_E     64
#define TPB        5                       // tiles per block (pass 1)
#define NTILES     (N_EDGES / TILE_E)      // 12500
#define GRID1      (NTILES / TPB)          // 2500
#define STAT_SLOTS 32
#define ZSTRIDE    200   // bf16 elems per FULL z row (fallback kernel LDS)
#define ZAST       136   // bf16 elems per 2-seg z row (main kernel: 128 + 8 pad)
#define NSCANBLK   ((N_ATOMS + 255) / 256) // 196

typedef __attribute__((ext_vector_type(8))) __bf16 bf16x8;
typedef __attribute__((ext_vector_type(4))) float  f32x4;
typedef __attribute__((ext_vector_type(4))) unsigned short u16x4;
typedef __attribute__((ext_vector_type(8))) unsigned short u16x8;

__device__ __forceinline__ ushort f2bf(float f) {
    union { float f; unsigned u; } v; v.f = f;
    unsigned u = v.u;
    return (ushort)((u + 0x7FFFu + ((u >> 16) & 1u)) >> 16);
}
__device__ __forceinline__ float bf2f(unsigned hi16) {
    union { unsigned u; float f; } v; v.u = hi16 << 16; return v.f;
}
// BN + sigmoid*softplus message from packed (core | filter<<16) bf16 pair
__device__ __forceinline__ float msgf(unsigned pv, float sc_c, float sh_c,
                                      float sc_f, float sh_f) {
    float pc = fmaf(bf2f(pv & 0xFFFFu), sc_c, sh_c);
    float pf = fmaf(bf2f(pv >> 16),     sc_f, sh_f);
    float sp = fmaxf(pc, 0.f) + __logf(1.f + __expf(-fabsf(pc)));
    float sg = 1.f / (1.f + __expf(-pf));
    return sp * sg;
}

// ---------------------------------------------------------------------------
// Gather split (ATOM segments only for main kernel): issue (global->regs) /
// commit (bf16 convert -> LDS). 16 lanes read one 256B atom row contiguously
// (4 whole rows per instruction) -- this coalescing is why FETCH stays low.
// eidx read directly from global (16 threads/edge share -> L1 broadcast).
// ---------------------------------------------------------------------------
__device__ __forceinline__ void gather_issue_a(
    const float* __restrict__ atom, const int* __restrict__ eidx,
    int tilebase, int tid, f32x4* v)
{
    const int er = tid >> 4, f4 = tid & 15;
#pragma unroll
    for (int it = 0; it < 8; ++it) {
        const int seg = it >> 2;                 // 0=dst, 1=src
        const int e   = (it & 3) * 16 + er;
        const float* srcp =
            atom + (size_t)eidx[2 * (tilebase + e) + (seg == 0 ? 1 : 0)] * 64;
        v[it] = *(const f32x4*)(srcp + f4 * 4);
    }
}

__device__ __forceinline__ void gather_commit_a(const f32x4* v, ushort* zl, int tid)
{
    const int er = tid >> 4, f4 = tid & 15;
#pragma unroll
    for (int it = 0; it < 8; ++it) {
        const int seg = it >> 2;
        const int e   = (it & 3) * 16 + er;
        u16x4 b;
        b.x = f2bf(v[it].x); b.y = f2bf(v[it].y);
        b.z = f2bf(v[it].z); b.w = f2bf(v[it].w);
        *(u16x4*)&zl[e * ZAST + seg * 64 + f4 * 4] = b;
    }
}

// Full-z gather helpers (fallback kernel only)
__device__ __forceinline__ void gather_issue(
    const float* __restrict__ atom, const float* __restrict__ edgef,
    const int* __restrict__ eidx, int tilebase, int tid, f32x4* v)
{
    const int er = tid >> 4, f4 = tid & 15;
#pragma unroll
    for (int it = 0; it < 12; ++it) {
        const int seg = it >> 2;
        const int e   = (it & 3) * 16 + er;
        const float* srcp;
        if (seg == 0)      srcp = atom  + (size_t)eidx[2 * (tilebase + e) + 1] * 64;
        else if (seg == 1) srcp = atom  + (size_t)eidx[2 * (tilebase + e)] * 64;
        else               srcp = edgef + (size_t)(tilebase + e) * 64;
        v[it] = *(const f32x4*)(srcp + f4 * 4);
    }
}

__device__ __forceinline__ void gather_commit(const f32x4* v, ushort* zl, int tid)
{
    const int er = tid >> 4, f4 = tid & 15;
#pragma unroll
    for (int it = 0; it < 12; ++it) {
        const int seg = it >> 2;
        const int e   = (it & 3) * 16 + er;
        u16x4 b;
        b.x = f2bf(v[it].x); b.y = f2bf(v[it].y);
        b.z = f2bf(v[it].z); b.w = f2bf(v[it].w);
        *(u16x4*)&zl[e * ZSTRIDE + seg * 64 + f4 * 4] = b;
    }
}

// ---------------------------------------------------------------------------
// Pass 1: prefetch-double-buffered atom gather + MFMA dual-GEMM + col sum/sumsq.
// Edge-feature A-fragments (ks=4,5) load DIRECTLY from global in fragment
// layout; LDS = 36.1KB -> 4 blocks/CU.
// WEIGHTS ARE STREAMED FROM GLOBAL (L2-resident 48KB table) inside the k-loop
// instead of a 96-VGPR register array -- '#pragma unroll 1' keeps the loads
// in-loop so the allocator can't rebuild the array (round-2 spill lesson).
// Pre-act rows stored PERMUTED to CSR slots (perm[e]); bias dropped (BN).
// One __syncthreads per tile: commit(t) | sync | issue(t+1) | MFMA(t)+store.
// ---------------------------------------------------------------------------
__global__ __launch_bounds__(256) void gemm_stats_store(
    const float* __restrict__ atom, const float* __restrict__ edgef,
    const ushort* __restrict__ Wb, const int* __restrict__ eidx,
    const unsigned* __restrict__ perm,
    float* __restrict__ stat_partial, unsigned* __restrict__ ws_pre,
    int do_store)
{
    __shared__ __align__(16) ushort zbuf[2][TILE_E * ZAST]; // 2x17.0KB
    __shared__ unsigned perml[TPB * TILE_E];                // 1.25KB
    const int tid  = threadIdx.x;
    const int lane = tid & 63, wave = tid >> 6;
    const int ch = wave >> 1, rp = wave & 1;
    const int row = lane & 15, quad = lane >> 4;

    const int t0 = blockIdx.x * TPB;
    for (int i = tid; i < TPB * TILE_E; i += 256)
        perml[i] = perm[t0 * TILE_E + i];

    float s[2][2] = {{0.f, 0.f}, {0.f, 0.f}};
    float q[2][2] = {{0.f, 0.f}, {0.f, 0.f}};

    // per-wave weight base: rows (m*64 + ch*32 + nt*16 + row), col chunk quad*8
    const ushort* wrow = Wb + (size_t)(ch * 32 + row) * KDIM + quad * 8;

    f32x4 pre[8];
    gather_issue_a(atom, eidx, t0 * TILE_E, tid, pre);

    for (int tt = 0; tt < TPB; ++tt) {
        ushort* zl = zbuf[tt & 1];
        gather_commit_a(pre, zl, tid);
        __syncthreads();   // zl visible; also protects buffer reuse
        if (tt + 1 < TPB)
            gather_issue_a(atom, eidx, (t0 + tt + 1) * TILE_E, tid, pre);

#pragma unroll
        for (int ett = 0; ett < 2; ++ett) {
            // direct edge-feature fragment loads (z cols 128..191)
            const size_t ebase =
                (size_t)((t0 + tt) * TILE_E + (2 * rp + ett) * 16 + row) * 64;
            f32x4 ef0 = *(const f32x4*)&edgef[ebase + quad * 8];
            f32x4 ef1 = *(const f32x4*)&edgef[ebase + quad * 8 + 4];
            f32x4 ef2 = *(const f32x4*)&edgef[ebase + 32 + quad * 8];
            f32x4 ef3 = *(const f32x4*)&edgef[ebase + 32 + quad * 8 + 4];

            const ushort* zb = zl + ((2 * rp + ett) * 16 + row) * ZAST;

            bf16x8 a4, a5;
            {
                union { u16x8 u; bf16x8 b; } t4, t5;
#pragma unroll
                for (int j = 0; j < 4; ++j) {
                    t4.u[j]     = f2bf(ef0[j]);
                    t4.u[4 + j] = f2bf(ef1[j]);
                    t5.u[j]     = f2bf(ef2[j]);
                    t5.u[4 + j] = f2bf(ef3[j]);
                }
                a4 = t4.b; a5 = t5.b;
            }

            f32x4 acc[2][2];
#pragma unroll
            for (int m = 0; m < 2; ++m)
#pragma unroll
                for (int nt = 0; nt < 2; ++nt)
                    acc[m][nt] = (f32x4){0.f, 0.f, 0.f, 0.f};

            // ks 0..3: A from LDS, B streamed from L2-resident weight table.
            // unroll 1 => loads stay in-loop => bounded register pressure.
#pragma unroll 1
            for (int ks = 0; ks < 4; ++ks) {
                bf16x8 av = *(const bf16x8*)&zb[ks * 32 + quad * 8];
                const ushort* wk = wrow + ks * 32;
                acc[0][0] = __builtin_amdgcn_mfma_f32_16x16x32_bf16(
                    av, *(const bf16x8*)&wk[0],                    acc[0][0], 0, 0, 0);
                acc[0][1] = __builtin_amdgcn_mfma_f32_16x16x32_bf16(
                    av, *(const bf16x8*)&wk[(size_t)16 * KDIM],    acc[0][1], 0, 0, 0);
                acc[1][0] = __builtin_amdgcn_mfma_f32_16x16x32_bf16(
                    av, *(const bf16x8*)&wk[(size_t)64 * KDIM],    acc[1][0], 0, 0, 0);
                acc[1][1] = __builtin_amdgcn_mfma_f32_16x16x32_bf16(
                    av, *(const bf16x8*)&wk[(size_t)80 * KDIM],    acc[1][1], 0, 0, 0);
            }
            // ks 4,5: A = ef register fragments (static tail, no runtime idx)
#pragma unroll
            for (int ks = 4; ks < 6; ++ks) {
                bf16x8 av = (ks == 4) ? a4 : a5;
                const ushort* wk = wrow + ks * 32;
                acc[0][0] = __builtin_amdgcn_mfma_f32_16x16x32_bf16(
                    av, *(const bf16x8*)&wk[0],                    acc[0][0], 0, 0, 0);
                acc[0][1] = __builtin_amdgcn_mfma_f32_16x16x32_bf16(
                    av, *(const bf16x8*)&wk[(size_t)16 * KDIM],    acc[0][1], 0, 0, 0);
                acc[1][0] = __builtin_amdgcn_mfma_f32_16x16x32_bf16(
                    av, *(const bf16x8*)&wk[(size_t)64 * KDIM],    acc[1][0], 0, 0, 0);
                acc[1][1] = __builtin_amdgcn_mfma_f32_16x16x32_bf16(
                    av, *(const bf16x8*)&wk[(size_t)80 * KDIM],    acc[1][1], 0, 0, 0);
            }

#pragma unroll
            for (int nt = 0; nt < 2; ++nt) {
                const int c = ch * 32 + nt * 16 + row;
#pragma unroll
                for (int r = 0; r < 4; ++r) {
                    float vc = acc[0][nt][r], vf = acc[1][nt][r];
                    s[0][nt] += vc; q[0][nt] += vc * vc;
                    s[1][nt] += vf; q[1][nt] += vf * vf;
                    if (do_store) {
                        const int eloc = (2 * rp + ett) * 16 + quad * 4 + r;
                        const unsigned pos = perml[tt * TILE_E + eloc];
                        unsigned pack = (unsigned)f2bf(vc) | ((unsigned)f2bf(vf) << 16);
                        ws_pre[(size_t)pos * 64 + c] = pack;  // plain store: L2 merges
                    }
                }
            }
        }
    }

    float* slot = stat_partial + (size_t)(blockIdx.x & (STAT_SLOTS - 1)) * 256;
#pragma unroll
    for (int m = 0; m < 2; ++m)
#pragma unroll
        for (int nt = 0; nt < 2; ++nt) {
            float sv = s[m][nt], qv = q[m][nt];
            sv += __shfl_xor(sv, 16, 64); sv += __shfl_xor(sv, 32, 64);
            qv += __shfl_xor(qv, 16, 64); qv += __shfl_xor(qv, 32, 64);
            if (lane < 16) {
                int c = ch * 32 + nt * 16 + lane;
                atomicAdd(slot + m * 128 + c, sv);
                atomicAdd(slot + m * 128 + 64 + c, qv);
            }
        }
}

// ---------------------------------------------------------------------------
// Fold BN into per-column scale/shift.
// params: [0..63]=scale_c [64..127]=scale_f [128..191]=shift_c [192..255]=shift_f
// ---------------------------------------------------------------------------
__global__ void finalize_stats(const float* __restrict__ stat_partial,
                               const float* __restrict__ gc, const float* __restrict__ btc,
                               const float* __restrict__ gf, const float* __restrict__ btf,
                               float* __restrict__ params)
{
    int t = threadIdx.x;            // 0..127
    bool isf = t >= 64;
    int j = t & 63;
    float s = 0.f, q = 0.f;
    for (int slot = 0; slot < STAT_SLOTS; slot++) {
        const float* sp = stat_partial + (size_t)slot * 256 + (isf ? 128 : 0);
        s += sp[j];
        q += sp[64 + j];
    }
    float mean = s / (float)N_EDGES;
    float var  = q / (float)N_EDGES - mean * mean;
    float inv  = rsqrtf(var + BN_EPS);
    float gamma = isf ? gf[j] : gc[j];
    float beta  = isf ? btf[j] : btc[j];
    float scale = gamma * inv;
    float shift = beta - mean * scale;
    params[t]       = scale;
    params[128 + t] = shift;
}

__global__ __launch_bounds__(256) void convert_weights(
    const float* __restrict__ Wc, const float* __restrict__ Wf,
    ushort* __restrict__ Wb)
{
    int i = blockIdx.x * 256 + threadIdx.x;
    float v = (i < 64 * KDIM) ? Wc[i] : Wf[i - 64 * KDIM];
    Wb[i] = f2bf(v);
}

// ---------------------------------------------------------------------------
// CSR-slot assignment: histogram -> 2-level exclusive scan -> cursors ->
// perm[e] = slot (coalesced write; no scattered csr array).
// ---------------------------------------------------------------------------
__global__ __launch_bounds__(256) void hist_dst(const int* __restrict__ eidx,
                                                unsigned* __restrict__ counts)
{
    int e = blockIdx.x * 256 + threadIdx.x;          // 3125 blocks
    atomicAdd(&counts[eidx[2 * e + 1]], 1u);
}

__global__ __launch_bounds__(256) void scan_a(const unsigned* __restrict__ counts,
                                              unsigned* __restrict__ row_start,
                                              unsigned* __restrict__ blksum)
{
    __shared__ unsigned sh[256];
    const int tid = threadIdx.x;
    const int i = blockIdx.x * 256 + tid;
    unsigned v = (i < N_ATOMS) ? counts[i] : 0u;
    sh[tid] = v;
    __syncthreads();
    for (int off = 1; off < 256; off <<= 1) {
        unsigned t = (tid >= off) ? sh[tid - off] : 0u;
        __syncthreads();
        sh[tid] += t;
        __syncthreads();
    }
    if (i < N_ATOMS) row_start[i] = sh[tid] - v;     // exclusive
    if (tid == 255) blksum[blockIdx.x] = sh[tid];
}

__global__ void scan_b(unsigned* __restrict__ blksum)   // 1 block
{
    __shared__ unsigned sh[256];
    const int tid = threadIdx.x;
    unsigned v = (tid < NSCANBLK) ? blksum[tid] : 0u;
    sh[tid] = v;
    __syncthreads();
    for (int off = 1; off < 256; off <<= 1) {
        unsigned t = (tid >= off) ? sh[tid - off] : 0u;
        __syncthreads();
        sh[tid] += t;
        __syncthreads();
    }
    if (tid < NSCANBLK) blksum[tid] = sh[tid] - v;   // exclusive
}

__global__ __launch_bounds__(256) void init_cursor(unsigned* __restrict__ row_start,
                                                   const unsigned* __restrict__ blksum,
                                                   unsigned* __restrict__ cursors)
{
    int i = blockIdx.x * 256 + threadIdx.x;
    if (i < N_ATOMS) {
        unsigned base = row_start[i] + blksum[i >> 8];
        row_start[i] = base;
        cursors[i]   = base;
    }
    if (i == 0) row_start[N_ATOMS] = N_EDGES;
}

__global__ __launch_bounds__(256) void fill_perm(const int* __restrict__ eidx,
                                                 unsigned* __restrict__ cursors,
                                                 unsigned* __restrict__ perm)
{
    int e = blockIdx.x * 256 + threadIdx.x;
    int d = eidx[2 * e + 1];
    perm[e] = atomicAdd(&cursors[d], 1u);   // coalesced perm write
}

// ---------------------------------------------------------------------------
// Pass 3: streaming gather-reduce. ws_pre rows are already in CSR order, so
// each wave (one atom, lane = column) reads a CONTIGUOUS run of 256B rows.
// One plain store per atom; no atomics, no index indirection.
// ---------------------------------------------------------------------------
__global__ __launch_bounds__(256) void bn_act_reduce(
    const unsigned* __restrict__ ws_pre, const unsigned* __restrict__ row_start,
    const float* __restrict__ atom, const float* __restrict__ params,
    float* __restrict__ out)
{
    const int lane = threadIdx.x & 63;
    const int a    = blockIdx.x * 4 + (threadIdx.x >> 6);

    const float sc_c = params[lane],      sh_c = params[128 + lane];
    const float sc_f = params[64 + lane], sh_f = params[192 + lane];

    const unsigned jb = row_start[a];
    const unsigned n  = row_start[a + 1] - jb;
    const unsigned* base = ws_pre + (size_t)jb * 64 + lane;

    float acc = 0.f;
    unsigned k = 0;
    for (; k + 8 <= n; k += 8) {
        unsigned p[8];
#pragma unroll
        for (int u = 0; u < 8; ++u) p[u] = base[(size_t)(k + u) * 64];
#pragma unroll
        for (int u = 0; u < 8; ++u) acc += msgf(p[u], sc_c, sh_c, sc_f, sh_f);
    }
    for (; k < n; ++k) acc += msgf(base[(size_t)k * 64], sc_c, sh_c, sc_f, sh_f);

    out[(size_t)a * 64 + lane] = atom[(size_t)a * 64 + lane] + acc;
}

// ---------------------------------------------------------------------------
// Fallback path (ws too small): recompute GEMM + atomic scatter (no ws_pre).
// ---------------------------------------------------------------------------
__global__ __launch_bounds__(256) void copy_out(const f32x4* __restrict__ src,
                                                f32x4* __restrict__ dst)
{
    int i = blockIdx.x * blockDim.x + threadIdx.x;
    dst[i] = src[i];
}

__global__ __launch_bounds__(256) void apply_scatter_fb(
    const float* __restrict__ atom, const float* __restrict__ edgef,
    const ushort* __restrict__ Wb, const int* __restrict__ eidx,
    const float* __restrict__ params, float* __restrict__ out)
{
    __shared__ __align__(16) ushort zl[TILE_E * ZSTRIDE];
    const int tid  = threadIdx.x;
    const int lane = tid & 63, wave = tid >> 6;
    const int ch = wave >> 1, rp = wave & 1;
    const int row = lane & 15, quad = lane >> 4;

    bf16x8 bfr[2][2][6];
#pragma unroll
    for (int m = 0; m < 2; ++m)
#pragma unroll
        for (int nt = 0; nt < 2; ++nt)
#pragma unroll
            for (int ks = 0; ks < 6; ++ks)
                bfr[m][nt][ks] = *(const bf16x8*)&Wb[
                    (size_t)(m * 64 + ch * 32 + nt * 16 + row) * KDIM + ks * 32 + quad * 8];

    float scc[2], shc[2], scf[2], shf[2];
#pragma unroll
    for (int nt = 0; nt < 2; ++nt) {
        int c = ch * 32 + nt * 16 + row;
        scc[nt] = params[c];        shc[nt] = params[128 + c];
        scf[nt] = params[64 + c];   shf[nt] = params[192 + c];
    }

    const int t0 = blockIdx.x * TPB;
    for (int tt = 0; tt < TPB; ++tt) {
        const int tilebase = (t0 + tt) * TILE_E;
        f32x4 pre[12];
        gather_issue(atom, edgef, eidx, tilebase, tid, pre);
        __syncthreads();
        gather_commit(pre, zl, tid);
        __syncthreads();
#pragma unroll
        for (int ett = 0; ett < 2; ++ett) {
            const ushort* zb = zl + ((2 * rp + ett) * 16 + row) * ZSTRIDE;
            bf16x8 a[6];
#pragma unroll
            for (int ks = 0; ks < 6; ++ks)
                a[ks] = *(const bf16x8*)&zb[ks * 32 + quad * 8];
            f32x4 acc[2][2];
#pragma unroll
            for (int m = 0; m < 2; ++m)
#pragma unroll
                for (int nt = 0; nt < 2; ++nt)
                    acc[m][nt] = (f32x4){0.f, 0.f, 0.f, 0.f};
#pragma unroll
            for (int ks = 0; ks < 6; ++ks)
#pragma unroll
                for (int m = 0; m < 2; ++m)
#pragma unroll
                    for (int nt = 0; nt < 2; ++nt)
                        acc[m][nt] = __builtin_amdgcn_mfma_f32_16x16x32_bf16(
                            a[ks], bfr[m][nt][ks], acc[m][nt], 0, 0, 0);
#pragma unroll
            for (int nt = 0; nt < 2; ++nt) {
                int c = ch * 32 + nt * 16 + row;
#pragma unroll
                for (int r = 0; r < 4; ++r) {
                    float pc = fmaf(acc[0][nt][r], scc[nt], shc[nt]);
                    float pf = fmaf(acc[1][nt][r], scf[nt], shf[nt]);
                    float sp = fmaxf(pc, 0.f) + __logf(1.f + __expf(-fabsf(pc)));
                    float sg = 1.f / (1.f + __expf(-pf));
                    int eloc = (2 * rp + ett) * 16 + quad * 4 + r;
                    int d = eidx[2 * (tilebase + eloc) + 1];
                    atomicAdd(out + (size_t)d * 64 + c, sp * sg);
                }
            }
        }
    }
}

// ---------------------------------------------------------------------------
extern "C" void kernel_launch(void* const* d_in, const int* in_sizes, int n_in,
                              void* d_out, int out_size, void* d_ws, size_t ws_size,
                              hipStream_t stream)
{
    const float* atom  = (const float*)d_in[0];
    const float* edgef = (const float*)d_in[1];
    const float* Wf    = (const float*)d_in[2];
    const float* gf    = (const float*)d_in[4];
    const float* btf   = (const float*)d_in[5];
    const float* Wc    = (const float*)d_in[6];
    const float* gc    = (const float*)d_in[8];
    const float* btc   = (const float*)d_in[9];
    const int*   eidx  = (const int*)d_in[10];
    float* out = (float*)d_out;

    // workspace layout (ws_pre first keeps everything 16B-aligned)
    unsigned* ws_pre       = (unsigned*)d_ws;                          // N_EDGES*64
    float*    stat_partial = (float*)(ws_pre + (size_t)N_EDGES * 64);  // 8192 f32
    float*    params       = stat_partial + STAT_SLOTS * 256;          // 256 f32
    ushort*   Wb           = (ushort*)(params + 256);                  // 24576 bf16
    unsigned* counts       = (unsigned*)(Wb + 2 * 64 * KDIM);          // 50000
    unsigned* row_start    = counts + N_ATOMS;                         // 50001
    unsigned* blksum       = row_start + N_ATOMS + 1;                  // 256
    unsigned* cursors      = blksum + 256;                             // 50000
    unsigned* perm         = cursors + N_ATOMS;                        // 800000

    const size_t need_full = (size_t)((char*)(perm + N_EDGES) - (char*)d_ws);
    const int full = (ws_size >= need_full) ? 1 : 0;

    (void)hipMemsetAsync(stat_partial, 0, STAT_SLOTS * 256 * sizeof(float), stream);
    convert_weights<<<(2 * 64 * KDIM) / 256, 256, 0, stream>>>(Wc, Wf, Wb);

    if (full) {
        (void)hipMemsetAsync(counts, 0, N_ATOMS * sizeof(unsigned), stream);
        hist_dst<<<N_EDGES / 256, 256, 0, stream>>>(eidx, counts);
        scan_a<<<NSCANBLK, 256, 0, stream>>>(counts, row_start, blksum);
        scan_b<<<1, 256, 0, stream>>>(blksum);
        init_cursor<<<NSCANBLK, 256, 0, stream>>>(row_start, blksum, cursors);
        fill_perm<<<N_EDGES / 256, 256, 0, stream>>>(eidx, cursors, perm);
        gemm_stats_store<<<GRID1, 256, 0, stream>>>(atom, edgef, Wb, eidx, perm,
                                                    stat_partial, ws_pre, 1);
        finalize_stats<<<1, 128, 0, stream>>>(stat_partial, gc, btc, gf, btf, params);
        bn_act_reduce<<<N_ATOMS / 4, 256, 0, stream>>>(ws_pre, row_start,
                                                       atom, params, out);
    } else {
        gemm_stats_store<<<GRID1, 256, 0, stream>>>(atom, edgef, Wb, eidx,
                                                    (unsigned*)counts /*unused*/,
                                                    stat_partial, ws_pre, 0);
        finalize_stats<<<1, 128, 0, stream>>>(stat_partial, gc, btc, gf, btf, params);
        copy_out<<<(N_ATOMS * 64 / 4) / 256, 256, 0, stream>>>(
            (const f32x4*)atom, (f32x4*)out);
        apply_scatter_fb<<<GRID1, 256, 0, stream>>>(atom, edgef, Wb, eidx,
                                                    params, out);
    }
}

// Round 4
// 629.125 us; speedup vs baseline: 1.3742x; 1.1193x over previous
//
#include <hip/hip_runtime.h>
#include <hip/hip_bf16.h>
#include <math.h>

// Problem constants
#define N_ATOMS   50000
#define N_EDGES   800000
#define KDIM      192
#define BN_EPS    1e-5f

#define TILE_E     64
#define TPB        5                       // tiles per block (pass 1)
#define NTILES     (N_EDGES / TILE_E)      // 12500
#define GRID1      (NTILES / TPB)          // 2500
#define STAT_SLOTS 32
#define ZSTRIDE    200   // bf16 elems per FULL z row (fallback kernel LDS)
#define ZAST       136   // bf16 elems per 2-seg z row (main kernel: 128 + 8 pad)
#define NSCANBLK   ((N_ATOMS + 255) / 256) // 196

typedef __attribute__((ext_vector_type(8))) __bf16 bf16x8;
typedef __attribute__((ext_vector_type(4))) float  f32x4;
typedef __attribute__((ext_vector_type(4))) unsigned short u16x4;
typedef __attribute__((ext_vector_type(8))) unsigned short u16x8;

__device__ __forceinline__ ushort f2bf(float f) {
    union { float f; unsigned u; } v; v.f = f;
    unsigned u = v.u;
    return (ushort)((u + 0x7FFFu + ((u >> 16) & 1u)) >> 16);
}
__device__ __forceinline__ float bf2f(unsigned hi16) {
    union { unsigned u; float f; } v; v.u = hi16 << 16; return v.f;
}
// BN + sigmoid*softplus message from packed (core | filter<<16) bf16 pair
__device__ __forceinline__ float msgf(unsigned pv, float sc_c, float sh_c,
                                      float sc_f, float sh_f) {
    float pc = fmaf(bf2f(pv & 0xFFFFu), sc_c, sh_c);
    float pf = fmaf(bf2f(pv >> 16),     sc_f, sh_f);
    float sp = fmaxf(pc, 0.f) + __logf(1.f + __expf(-fabsf(pc)));
    float sg = 1.f / (1.f + __expf(-pf));
    return sp * sg;
}

// ---------------------------------------------------------------------------
// Gather split (ATOM segments only for main kernel): issue (global->regs) /
// commit (bf16 convert -> LDS). 16 lanes read one 256B atom row contiguously
// (4 whole rows per instruction) -- this coalescing is why FETCH stays low.
// eidx read directly from global (16 threads/edge share -> L1 broadcast).
// ---------------------------------------------------------------------------
__device__ __forceinline__ void gather_issue_a(
    const float* __restrict__ atom, const int* __restrict__ eidx,
    int tilebase, int tid, f32x4* v)
{
    const int er = tid >> 4, f4 = tid & 15;
#pragma unroll
    for (int it = 0; it < 8; ++it) {
        const int seg = it >> 2;                 // 0=dst, 1=src
        const int e   = (it & 3) * 16 + er;
        const float* srcp =
            atom + (size_t)eidx[2 * (tilebase + e) + (seg == 0 ? 1 : 0)] * 64;
        v[it] = *(const f32x4*)(srcp + f4 * 4);
    }
}

__device__ __forceinline__ void gather_commit_a(const f32x4* v, ushort* zl, int tid)
{
    const int er = tid >> 4, f4 = tid & 15;
#pragma unroll
    for (int it = 0; it < 8; ++it) {
        const int seg = it >> 2;
        const int e   = (it & 3) * 16 + er;
        u16x4 b;
        b.x = f2bf(v[it].x); b.y = f2bf(v[it].y);
        b.z = f2bf(v[it].z); b.w = f2bf(v[it].w);
        *(u16x4*)&zl[e * ZAST + seg * 64 + f4 * 4] = b;
    }
}

// Full-z gather helpers (fallback kernel only)
__device__ __forceinline__ void gather_issue(
    const float* __restrict__ atom, const float* __restrict__ edgef,
    const int* __restrict__ eidx, int tilebase, int tid, f32x4* v)
{
    const int er = tid >> 4, f4 = tid & 15;
#pragma unroll
    for (int it = 0; it < 12; ++it) {
        const int seg = it >> 2;
        const int e   = (it & 3) * 16 + er;
        const float* srcp;
        if (seg == 0)      srcp = atom  + (size_t)eidx[2 * (tilebase + e) + 1] * 64;
        else if (seg == 1) srcp = atom  + (size_t)eidx[2 * (tilebase + e)] * 64;
        else               srcp = edgef + (size_t)(tilebase + e) * 64;
        v[it] = *(const f32x4*)(srcp + f4 * 4);
    }
}

__device__ __forceinline__ void gather_commit(const f32x4* v, ushort* zl, int tid)
{
    const int er = tid >> 4, f4 = tid & 15;
#pragma unroll
    for (int it = 0; it < 12; ++it) {
        const int seg = it >> 2;
        const int e   = (it & 3) * 16 + er;
        u16x4 b;
        b.x = f2bf(v[it].x); b.y = f2bf(v[it].y);
        b.z = f2bf(v[it].z); b.w = f2bf(v[it].w);
        *(u16x4*)&zl[e * ZSTRIDE + seg * 64 + f4 * 4] = b;
    }
}

// ---------------------------------------------------------------------------
// Pass 1: prefetch-double-buffered atom gather + MFMA dual-GEMM + col sum/sumsq.
// Wave mapping (round-4): wave = COLUMN-GROUP. Each wave owns 16 output cols
// (c = wave*16 + row) of BOTH matrices and processes ALL 64 edges (ett 0..3).
// -> weight fragments = bfr[2][6] = 48 VGPR (half of round-0's 96), keeping
// the core|filter packed store and stats in one thread.
// Edge-feature A-fragments (ks=4,5) load DIRECTLY from global in fragment
// layout; LDS = 36.1KB -> 4 blocks/CU. Weights stay in registers, statically
// indexed, fully unrolled (round-3 lesson: never stream B per-k from global).
// No forced min-waves launch bound (round-2 lesson: forcing -> scratch spill).
// Pre-act rows stored PERMUTED to CSR slots (perm[e]); bias dropped (BN).
// One __syncthreads per tile: commit(t) | sync | issue(t+1) | MFMA(t)+store.
// ---------------------------------------------------------------------------
__global__ __launch_bounds__(256) void gemm_stats_store(
    const float* __restrict__ atom, const float* __restrict__ edgef,
    const ushort* __restrict__ Wb, const int* __restrict__ eidx,
    const unsigned* __restrict__ perm,
    float* __restrict__ stat_partial, unsigned* __restrict__ ws_pre,
    int do_store)
{
    __shared__ __align__(16) ushort zbuf[2][TILE_E * ZAST]; // 2x17.0KB
    __shared__ unsigned perml[TPB * TILE_E];                // 1.25KB
    const int tid  = threadIdx.x;
    const int lane = tid & 63, wave = tid >> 6;   // wave = col-group 0..3
    const int row = lane & 15, quad = lane >> 4;

    const int t0 = blockIdx.x * TPB;
    for (int i = tid; i < TPB * TILE_E; i += 256)
        perml[i] = perm[t0 * TILE_E + i];

    // 12 weight fragments: matrix m in {core,filter}, k-chunk ks, col c=wave*16+row
    bf16x8 bfr[2][6];
#pragma unroll
    for (int m = 0; m < 2; ++m)
#pragma unroll
        for (int ks = 0; ks < 6; ++ks)
            bfr[m][ks] = *(const bf16x8*)&Wb[
                (size_t)(m * 64 + wave * 16 + row) * KDIM + ks * 32 + quad * 8];

    float s0 = 0.f, q0 = 0.f, s1 = 0.f, q1 = 0.f;

    f32x4 pre[8];
    gather_issue_a(atom, eidx, t0 * TILE_E, tid, pre);

    for (int tt = 0; tt < TPB; ++tt) {
        ushort* zl = zbuf[tt & 1];
        gather_commit_a(pre, zl, tid);
        __syncthreads();   // zl visible; also protects buffer reuse
        if (tt + 1 < TPB)
            gather_issue_a(atom, eidx, (t0 + tt + 1) * TILE_E, tid, pre);

#pragma unroll
        for (int ett = 0; ett < 4; ++ett) {
            // direct edge-feature fragment loads (z cols 128..191), issued first
            const size_t ebase =
                (size_t)((t0 + tt) * TILE_E + ett * 16 + row) * 64;
            f32x4 ef0 = *(const f32x4*)&edgef[ebase + quad * 8];
            f32x4 ef1 = *(const f32x4*)&edgef[ebase + quad * 8 + 4];
            f32x4 ef2 = *(const f32x4*)&edgef[ebase + 32 + quad * 8];
            f32x4 ef3 = *(const f32x4*)&edgef[ebase + 32 + quad * 8 + 4];

            const ushort* zb = zl + (ett * 16 + row) * ZAST;

            f32x4 acc0 = (f32x4){0.f, 0.f, 0.f, 0.f};
            f32x4 acc1 = (f32x4){0.f, 0.f, 0.f, 0.f};

            // ks 0..3: A from LDS (fast), runs while ef loads are in flight
#pragma unroll
            for (int ks = 0; ks < 4; ++ks) {
                bf16x8 av = *(const bf16x8*)&zb[ks * 32 + quad * 8];
                acc0 = __builtin_amdgcn_mfma_f32_16x16x32_bf16(
                    av, bfr[0][ks], acc0, 0, 0, 0);
                acc1 = __builtin_amdgcn_mfma_f32_16x16x32_bf16(
                    av, bfr[1][ks], acc1, 0, 0, 0);
            }
            // ks 4,5: A = ef register fragments
            {
                union { u16x8 u; bf16x8 b; } t4, t5;
#pragma unroll
                for (int j = 0; j < 4; ++j) {
                    t4.u[j]     = f2bf(ef0[j]);
                    t4.u[4 + j] = f2bf(ef1[j]);
                    t5.u[j]     = f2bf(ef2[j]);
                    t5.u[4 + j] = f2bf(ef3[j]);
                }
                acc0 = __builtin_amdgcn_mfma_f32_16x16x32_bf16(
                    t4.b, bfr[0][4], acc0, 0, 0, 0);
                acc1 = __builtin_amdgcn_mfma_f32_16x16x32_bf16(
                    t4.b, bfr[1][4], acc1, 0, 0, 0);
                acc0 = __builtin_amdgcn_mfma_f32_16x16x32_bf16(
                    t5.b, bfr[0][5], acc0, 0, 0, 0);
                acc1 = __builtin_amdgcn_mfma_f32_16x16x32_bf16(
                    t5.b, bfr[1][5], acc1, 0, 0, 0);
            }

            const int c = wave * 16 + row;
#pragma unroll
            for (int r = 0; r < 4; ++r) {
                float vc = acc0[r], vf = acc1[r];
                s0 += vc; q0 += vc * vc;
                s1 += vf; q1 += vf * vf;
                if (do_store) {
                    const int eloc = ett * 16 + quad * 4 + r;
                    const unsigned pos = perml[tt * TILE_E + eloc];
                    unsigned pack = (unsigned)f2bf(vc) | ((unsigned)f2bf(vf) << 16);
                    ws_pre[(size_t)pos * 64 + c] = pack;  // plain store: L2 merges
                }
            }
        }
    }

    // stats: lanes sharing `row` across quads hold the same column
    float* slot = stat_partial + (size_t)(blockIdx.x & (STAT_SLOTS - 1)) * 256;
    s0 += __shfl_xor(s0, 16, 64); s0 += __shfl_xor(s0, 32, 64);
    q0 += __shfl_xor(q0, 16, 64); q0 += __shfl_xor(q0, 32, 64);
    s1 += __shfl_xor(s1, 16, 64); s1 += __shfl_xor(s1, 32, 64);
    q1 += __shfl_xor(q1, 16, 64); q1 += __shfl_xor(q1, 32, 64);
    if (lane < 16) {
        const int c = wave * 16 + lane;
        atomicAdd(slot + c,            s0);
        atomicAdd(slot + 64 + c,       q0);
        atomicAdd(slot + 128 + c,      s1);
        atomicAdd(slot + 192 + c,      q1);
    }
}

// ---------------------------------------------------------------------------
// Fold BN into per-column scale/shift.
// params: [0..63]=scale_c [64..127]=scale_f [128..191]=shift_c [192..255]=shift_f
// ---------------------------------------------------------------------------
__global__ void finalize_stats(const float* __restrict__ stat_partial,
                               const float* __restrict__ gc, const float* __restrict__ btc,
                               const float* __restrict__ gf, const float* __restrict__ btf,
                               float* __restrict__ params)
{
    int t = threadIdx.x;            // 0..127
    bool isf = t >= 64;
    int j = t & 63;
    float s = 0.f, q = 0.f;
    for (int slot = 0; slot < STAT_SLOTS; slot++) {
        const float* sp = stat_partial + (size_t)slot * 256 + (isf ? 128 : 0);
        s += sp[j];
        q += sp[64 + j];
    }
    float mean = s / (float)N_EDGES;
    float var  = q / (float)N_EDGES - mean * mean;
    float inv  = rsqrtf(var + BN_EPS);
    float gamma = isf ? gf[j] : gc[j];
    float beta  = isf ? btf[j] : btc[j];
    float scale = gamma * inv;
    float shift = beta - mean * scale;
    params[t]       = scale;
    params[128 + t] = shift;
}

__global__ __launch_bounds__(256) void convert_weights(
    const float* __restrict__ Wc, const float* __restrict__ Wf,
    ushort* __restrict__ Wb)
{
    int i = blockIdx.x * 256 + threadIdx.x;
    float v = (i < 64 * KDIM) ? Wc[i] : Wf[i - 64 * KDIM];
    Wb[i] = f2bf(v);
}

// ---------------------------------------------------------------------------
// CSR-slot assignment: histogram -> 2-level exclusive scan -> cursors ->
// perm[e] = slot (coalesced write; no scattered csr array).
// ---------------------------------------------------------------------------
__global__ __launch_bounds__(256) void hist_dst(const int* __restrict__ eidx,
                                                unsigned* __restrict__ counts)
{
    int e = blockIdx.x * 256 + threadIdx.x;          // 3125 blocks
    atomicAdd(&counts[eidx[2 * e + 1]], 1u);
}

__global__ __launch_bounds__(256) void scan_a(const unsigned* __restrict__ counts,
                                              unsigned* __restrict__ row_start,
                                              unsigned* __restrict__ blksum)
{
    __shared__ unsigned sh[256];
    const int tid = threadIdx.x;
    const int i = blockIdx.x * 256 + tid;
    unsigned v = (i < N_ATOMS) ? counts[i] : 0u;
    sh[tid] = v;
    __syncthreads();
    for (int off = 1; off < 256; off <<= 1) {
        unsigned t = (tid >= off) ? sh[tid - off] : 0u;
        __syncthreads();
        sh[tid] += t;
        __syncthreads();
    }
    if (i < N_ATOMS) row_start[i] = sh[tid] - v;     // exclusive
    if (tid == 255) blksum[blockIdx.x] = sh[tid];
}

__global__ void scan_b(unsigned* __restrict__ blksum)   // 1 block
{
    __shared__ unsigned sh[256];
    const int tid = threadIdx.x;
    unsigned v = (tid < NSCANBLK) ? blksum[tid] : 0u;
    sh[tid] = v;
    __syncthreads();
    for (int off = 1; off < 256; off <<= 1) {
        unsigned t = (tid >= off) ? sh[tid - off] : 0u;
        __syncthreads();
        sh[tid] += t;
        __syncthreads();
    }
    if (tid < NSCANBLK) blksum[tid] = sh[tid] - v;   // exclusive
}

__global__ __launch_bounds__(256) void init_cursor(unsigned* __restrict__ row_start,
                                                   const unsigned* __restrict__ blksum,
                                                   unsigned* __restrict__ cursors)
{
    int i = blockIdx.x * 256 + threadIdx.x;
    if (i < N_ATOMS) {
        unsigned base = row_start[i] + blksum[i >> 8];
        row_start[i] = base;
        cursors[i]   = base;
    }
    if (i == 0) row_start[N_ATOMS] = N_EDGES;
}

__global__ __launch_bounds__(256) void fill_perm(const int* __restrict__ eidx,
                                                 unsigned* __restrict__ cursors,
                                                 unsigned* __restrict__ perm)
{
    int e = blockIdx.x * 256 + threadIdx.x;
    int d = eidx[2 * e + 1];
    perm[e] = atomicAdd(&cursors[d], 1u);   // coalesced perm write
}

// ---------------------------------------------------------------------------
// Pass 3: streaming gather-reduce. ws_pre rows are already in CSR order, so
// each wave (one atom, lane = column) reads a CONTIGUOUS run of 256B rows.
// One plain store per atom; no atomics, no index indirection.
// ---------------------------------------------------------------------------
__global__ __launch_bounds__(256) void bn_act_reduce(
    const unsigned* __restrict__ ws_pre, const unsigned* __restrict__ row_start,
    const float* __restrict__ atom, const float* __restrict__ params,
    float* __restrict__ out)
{
    const int lane = threadIdx.x & 63;
    const int a    = blockIdx.x * 4 + (threadIdx.x >> 6);

    const float sc_c = params[lane],      sh_c = params[128 + lane];
    const float sc_f = params[64 + lane], sh_f = params[192 + lane];

    const unsigned jb = row_start[a];
    const unsigned n  = row_start[a + 1] - jb;
    const unsigned* base = ws_pre + (size_t)jb * 64 + lane;

    float acc = 0.f;
    unsigned k = 0;
    for (; k + 8 <= n; k += 8) {
        unsigned p[8];
#pragma unroll
        for (int u = 0; u < 8; ++u) p[u] = base[(size_t)(k + u) * 64];
#pragma unroll
        for (int u = 0; u < 8; ++u) acc += msgf(p[u], sc_c, sh_c, sc_f, sh_f);
    }
    for (; k < n; ++k) acc += msgf(base[(size_t)k * 64], sc_c, sh_c, sc_f, sh_f);

    out[(size_t)a * 64 + lane] = atom[(size_t)a * 64 + lane] + acc;
}

// ---------------------------------------------------------------------------
// Fallback path (ws too small): recompute GEMM + atomic scatter (no ws_pre).
// ---------------------------------------------------------------------------
__global__ __launch_bounds__(256) void copy_out(const f32x4* __restrict__ src,
                                                f32x4* __restrict__ dst)
{
    int i = blockIdx.x * blockDim.x + threadIdx.x;
    dst[i] = src[i];
}

__global__ __launch_bounds__(256) void apply_scatter_fb(
    const float* __restrict__ atom, const float* __restrict__ edgef,
    const ushort* __restrict__ Wb, const int* __restrict__ eidx,
    const float* __restrict__ params, float* __restrict__ out)
{
    __shared__ __align__(16) ushort zl[TILE_E * ZSTRIDE];
    const int tid  = threadIdx.x;
    const int lane = tid & 63, wave = tid >> 6;
    const int ch = wave >> 1, rp = wave & 1;
    const int row = lane & 15, quad = lane >> 4;

    bf16x8 bfr[2][2][6];
#pragma unroll
    for (int m = 0; m < 2; ++m)
#pragma unroll
        for (int nt = 0; nt < 2; ++nt)
#pragma unroll
            for (int ks = 0; ks < 6; ++ks)
                bfr[m][nt][ks] = *(const bf16x8*)&Wb[
                    (size_t)(m * 64 + ch * 32 + nt * 16 + row) * KDIM + ks * 32 + quad * 8];

    float scc[2], shc[2], scf[2], shf[2];
#pragma unroll
    for (int nt = 0; nt < 2; ++nt) {
        int c = ch * 32 + nt * 16 + row;
        scc[nt] = params[c];        shc[nt] = params[128 + c];
        scf[nt] = params[64 + c];   shf[nt] = params[192 + c];
    }

    const int t0 = blockIdx.x * TPB;
    for (int tt = 0; tt < TPB; ++tt) {
        const int tilebase = (t0 + tt) * TILE_E;
        f32x4 pre[12];
        gather_issue(atom, edgef, eidx, tilebase, tid, pre);
        __syncthreads();
        gather_commit(pre, zl, tid);
        __syncthreads();
#pragma unroll
        for (int ett = 0; ett < 2; ++ett) {
            const ushort* zb = zl + ((2 * rp + ett) * 16 + row) * ZSTRIDE;
            bf16x8 a[6];
#pragma unroll
            for (int ks = 0; ks < 6; ++ks)
                a[ks] = *(const bf16x8*)&zb[ks * 32 + quad * 8];
            f32x4 acc[2][2];
#pragma unroll
            for (int m = 0; m < 2; ++m)
#pragma unroll
                for (int nt = 0; nt < 2; ++nt)
                    acc[m][nt] = (f32x4){0.f, 0.f, 0.f, 0.f};
#pragma unroll
            for (int ks = 0; ks < 6; ++ks)
#pragma unroll
                for (int m = 0; m < 2; ++m)
#pragma unroll
                    for (int nt = 0; nt < 2; ++nt)
                        acc[m][nt] = __builtin_amdgcn_mfma_f32_16x16x32_bf16(
                            a[ks], bfr[m][nt][ks], acc[m][nt], 0, 0, 0);
#pragma unroll
            for (int nt = 0; nt < 2; ++nt) {
                int c = ch * 32 + nt * 16 + row;
#pragma unroll
                for (int r = 0; r < 4; ++r) {
                    float pc = fmaf(acc[0][nt][r], scc[nt], shc[nt]);
                    float pf = fmaf(acc[1][nt][r], scf[nt], shf[nt]);
                    float sp = fmaxf(pc, 0.f) + __logf(1.f + __expf(-fabsf(pc)));
                    float sg = 1.f / (1.f + __expf(-pf));
                    int eloc = (2 * rp + ett) * 16 + quad * 4 + r;
                    int d = eidx[2 * (tilebase + eloc) + 1];
                    atomicAdd(out + (size_t)d * 64 + c, sp * sg);
                }
            }
        }
    }
}

// ---------------------------------------------------------------------------
extern "C" void kernel_launch(void* const* d_in, const int* in_sizes, int n_in,
                              void* d_out, int out_size, void* d_ws, size_t ws_size,
                              hipStream_t stream)
{
    const float* atom  = (const float*)d_in[0];
    const float* edgef = (const float*)d_in[1];
    const float* Wf    = (const float*)d_in[2];
    const float* gf    = (const float*)d_in[4];
    const float* btf   = (const float*)d_in[5];
    const float* Wc    = (const float*)d_in[6];
    const float* gc    = (const float*)d_in[8];
    const float* btc   = (const float*)d_in[9];
    const int*   eidx  = (const int*)d_in[10];
    float* out = (float*)d_out;

    // workspace layout (ws_pre first keeps everything 16B-aligned)
    unsigned* ws_pre       = (unsigned*)d_ws;                          // N_EDGES*64
    float*    stat_partial = (float*)(ws_pre + (size_t)N_EDGES * 64);  // 8192 f32
    float*    params       = stat_partial + STAT_SLOTS * 256;          // 256 f32
    ushort*   Wb           = (ushort*)(params + 256);                  // 24576 bf16
    unsigned* counts       = (unsigned*)(Wb + 2 * 64 * KDIM);          // 50000
    unsigned* row_start    = counts + N_ATOMS;                         // 50001
    unsigned* blksum       = row_start + N_ATOMS + 1;                  // 256
    unsigned* cursors      = blksum + 256;                             // 50000
    unsigned* perm         = cursors + N_ATOMS;                        // 800000

    const size_t need_full = (size_t)((char*)(perm + N_EDGES) - (char*)d_ws);
    const int full = (ws_size >= need_full) ? 1 : 0;

    (void)hipMemsetAsync(stat_partial, 0, STAT_SLOTS * 256 * sizeof(float), stream);
    convert_weights<<<(2 * 64 * KDIM) / 256, 256, 0, stream>>>(Wc, Wf, Wb);

    if (full) {
        (void)hipMemsetAsync(counts, 0, N_ATOMS * sizeof(unsigned), stream);
        hist_dst<<<N_EDGES / 256, 256, 0, stream>>>(eidx, counts);
        scan_a<<<NSCANBLK, 256, 0, stream>>>(counts, row_start, blksum);
        scan_b<<<1, 256, 0, stream>>>(blksum);
        init_cursor<<<NSCANBLK, 256, 0, stream>>>(row_start, blksum, cursors);
        fill_perm<<<N_EDGES / 256, 256, 0, stream>>>(eidx, cursors, perm);
        gemm_stats_store<<<GRID1, 256, 0, stream>>>(atom, edgef, Wb, eidx, perm,
                                                    stat_partial, ws_pre, 1);
        finalize_stats<<<1, 128, 0, stream>>>(stat_partial, gc, btc, gf, btf, params);
        bn_act_reduce<<<N_ATOMS / 4, 256, 0, stream>>>(ws_pre, row_start,
                                                       atom, params, out);
    } else {
        gemm_stats_store<<<GRID1, 256, 0, stream>>>(atom, edgef, Wb, eidx,
                                                    (unsigned*)counts /*unused*/,
                                                    stat_partial, ws_pre, 0);
        finalize_stats<<<1, 128, 0, stream>>>(stat_partial, gc, btc, gf, btf, params);
        copy_out<<<(N_ATOMS * 64 / 4) / 256, 256, 0, stream>>>(
            (const f32x4*)atom, (f32x4*)out);
        apply_scatter_fb<<<GRID1, 256, 0, stream>>>(atom, edgef, Wb, eidx,
                                                    params, out);
    }
}

// Round 5
// 551.930 us; speedup vs baseline: 1.5664x; 1.1399x over previous
//
#include <hip/hip_runtime.h>
#include <hip/hip_bf16.h>
#include <math.h>

// Problem constants
#define N_ATOMS   50000
#define N_EDGES   800000
#define KDIM      192
#define BN_EPS    1e-5f

#define TILE_E     64
#define TPB        5                       // tiles per block (pass 1)
#define NTILES     (N_EDGES / TILE_E)      // 12500
#define GRID1      (NTILES / TPB)          // 2500
#define STAT_SLOTS 32
#define ZSTRIDE    200   // bf16 elems per z row (192 + 8 pad, 16B-aligned rows)
#define NSCANBLK   ((N_ATOMS + 255) / 256) // 196

typedef __attribute__((ext_vector_type(8))) __bf16 bf16x8;
typedef __attribute__((ext_vector_type(4))) float  f32x4;
typedef __attribute__((ext_vector_type(4))) unsigned short u16x4;

__device__ __forceinline__ ushort f2bf(float f) {
    union { float f; unsigned u; } v; v.f = f;
    unsigned u = v.u;
    return (ushort)((u + 0x7FFFu + ((u >> 16) & 1u)) >> 16);
}
__device__ __forceinline__ float bf2f(unsigned hi16) {
    union { unsigned u; float f; } v; v.u = hi16 << 16; return v.f;
}
// BN + sigmoid*softplus message from packed (core | filter<<16) bf16 pair
__device__ __forceinline__ float msgf(unsigned pv, float sc_c, float sh_c,
                                      float sc_f, float sh_f) {
    float pc = fmaf(bf2f(pv & 0xFFFFu), sc_c, sh_c);
    float pf = fmaf(bf2f(pv >> 16),     sc_f, sh_f);
    float sp = fmaxf(pc, 0.f) + __logf(1.f + __expf(-fabsf(pc)));
    float sg = 1.f / (1.f + __expf(-pf));
    return sp * sg;
}

// ---------------------------------------------------------------------------
// Gather split: issue (global loads -> regs) / commit (bf16 convert -> LDS).
// eidx is read directly from global (16 threads/edge share -> L1 broadcast).
// (Round-0 proven structure: 16 lanes read one 256B row contiguously.)
// ---------------------------------------------------------------------------
__device__ __forceinline__ void gather_issue(
    const float* __restrict__ atom, const float* __restrict__ edgef,
    const int* __restrict__ eidx, int tilebase, int tid, f32x4* v)
{
    const int er = tid >> 4, f4 = tid & 15;
#pragma unroll
    for (int it = 0; it < 12; ++it) {
        const int seg = it >> 2;
        const int e   = (it & 3) * 16 + er;
        const float* srcp;
        if (seg == 0)      srcp = atom  + (size_t)eidx[2 * (tilebase + e) + 1] * 64;
        else if (seg == 1) srcp = atom  + (size_t)eidx[2 * (tilebase + e)] * 64;
        else               srcp = edgef + (size_t)(tilebase + e) * 64;
        v[it] = *(const f32x4*)(srcp + f4 * 4);
    }
}

__device__ __forceinline__ void gather_commit(const f32x4* v, ushort* zl, int tid)
{
    const int er = tid >> 4, f4 = tid & 15;
#pragma unroll
    for (int it = 0; it < 12; ++it) {
        const int seg = it >> 2;
        const int e   = (it & 3) * 16 + er;
        u16x4 b;
        b.x = f2bf(v[it].x); b.y = f2bf(v[it].y);
        b.z = f2bf(v[it].z); b.w = f2bf(v[it].w);
        *(u16x4*)&zl[e * ZSTRIDE + seg * 64 + f4 * 4] = b;
    }
}

// ---------------------------------------------------------------------------
// Pass 1 (EXACT round-0 structure, the 163us champion): prefetch-double-
// buffered gather + MFMA dual-GEMM + column sum/sumsq. Pre-act rows stored
// PERMUTED to CSR slots (perm[e]) so the reduce pass streams sequentially.
// Bias dropped (cancels under BN).
// One __syncthreads per tile: commit(t) | sync | issue(t+1) | MFMA(t)+store.
// ---------------------------------------------------------------------------
__global__ __launch_bounds__(256) void gemm_stats_store(
    const float* __restrict__ atom, const float* __restrict__ edgef,
    const ushort* __restrict__ Wb, const int* __restrict__ eidx,
    const unsigned* __restrict__ perm,
    float* __restrict__ stat_partial, unsigned* __restrict__ ws_pre,
    int do_store)
{
    __shared__ __align__(16) ushort zbuf[2][TILE_E * ZSTRIDE]; // 2x25.6KB
    __shared__ unsigned perml[TPB * TILE_E];                   // 1.25KB
    const int tid  = threadIdx.x;
    const int lane = tid & 63, wave = tid >> 6;
    const int ch = wave >> 1, rp = wave & 1;
    const int row = lane & 15, quad = lane >> 4;

    const int t0 = blockIdx.x * TPB;
    for (int i = tid; i < TPB * TILE_E; i += 256)
        perml[i] = perm[t0 * TILE_E + i];

    bf16x8 bfr[2][2][6];
#pragma unroll
    for (int m = 0; m < 2; ++m)
#pragma unroll
        for (int nt = 0; nt < 2; ++nt)
#pragma unroll
            for (int ks = 0; ks < 6; ++ks)
                bfr[m][nt][ks] = *(const bf16x8*)&Wb[
                    (size_t)(m * 64 + ch * 32 + nt * 16 + row) * KDIM + ks * 32 + quad * 8];

    float s[2][2] = {{0.f, 0.f}, {0.f, 0.f}};
    float q[2][2] = {{0.f, 0.f}, {0.f, 0.f}};

    f32x4 pre[12];
    gather_issue(atom, edgef, eidx, t0 * TILE_E, tid, pre);

    for (int tt = 0; tt < TPB; ++tt) {
        ushort* zl = zbuf[tt & 1];
        gather_commit(pre, zl, tid);
        __syncthreads();   // zl visible; also protects buffer reuse
        if (tt + 1 < TPB)
            gather_issue(atom, edgef, eidx, (t0 + tt + 1) * TILE_E, tid, pre);

#pragma unroll
        for (int ett = 0; ett < 2; ++ett) {
            const ushort* zb = zl + ((2 * rp + ett) * 16 + row) * ZSTRIDE;
            bf16x8 a[6];
#pragma unroll
            for (int ks = 0; ks < 6; ++ks)
                a[ks] = *(const bf16x8*)&zb[ks * 32 + quad * 8];
            f32x4 acc[2][2];
#pragma unroll
            for (int m = 0; m < 2; ++m)
#pragma unroll
                for (int nt = 0; nt < 2; ++nt)
                    acc[m][nt] = (f32x4){0.f, 0.f, 0.f, 0.f};
#pragma unroll
            for (int ks = 0; ks < 6; ++ks)
#pragma unroll
                for (int m = 0; m < 2; ++m)
#pragma unroll
                    for (int nt = 0; nt < 2; ++nt)
                        acc[m][nt] = __builtin_amdgcn_mfma_f32_16x16x32_bf16(
                            a[ks], bfr[m][nt][ks], acc[m][nt], 0, 0, 0);
#pragma unroll
            for (int nt = 0; nt < 2; ++nt) {
                const int c = ch * 32 + nt * 16 + row;
#pragma unroll
                for (int r = 0; r < 4; ++r) {
                    float vc = acc[0][nt][r], vf = acc[1][nt][r];
                    s[0][nt] += vc; q[0][nt] += vc * vc;
                    s[1][nt] += vf; q[1][nt] += vf * vf;
                    if (do_store) {
                        const int eloc = (2 * rp + ett) * 16 + quad * 4 + r;
                        const unsigned pos = perml[tt * TILE_E + eloc];
                        unsigned pack = (unsigned)f2bf(vc) | ((unsigned)f2bf(vf) << 16);
                        ws_pre[(size_t)pos * 64 + c] = pack;  // plain store: L2 merges
                    }
                }
            }
        }
    }

    float* slot = stat_partial + (size_t)(blockIdx.x & (STAT_SLOTS - 1)) * 256;
#pragma unroll
    for (int m = 0; m < 2; ++m)
#pragma unroll
        for (int nt = 0; nt < 2; ++nt) {
            float sv = s[m][nt], qv = q[m][nt];
            sv += __shfl_xor(sv, 16, 64); sv += __shfl_xor(sv, 32, 64);
            qv += __shfl_xor(qv, 16, 64); qv += __shfl_xor(qv, 32, 64);
            if (lane < 16) {
                int c = ch * 32 + nt * 16 + lane;
                atomicAdd(slot + m * 128 + c, sv);
                atomicAdd(slot + m * 128 + 64 + c, qv);
            }
        }
}

// ---------------------------------------------------------------------------
// Fused setup: zero stat_partial + counts + cursors, convert weights to bf16.
// Replaces 2 hipMemsetAsync + convert_weights (dispatch-count reduction).
// ---------------------------------------------------------------------------
__global__ __launch_bounds__(256) void setup_all(
    const float* __restrict__ Wc, const float* __restrict__ Wf,
    ushort* __restrict__ Wb, float* __restrict__ stat_partial,
    unsigned* __restrict__ counts, unsigned* __restrict__ cursors)
{
    int i = blockIdx.x * 256 + threadIdx.x;       // 256 blocks -> 65536 threads
    if (i < 2 * 64 * KDIM) {
        float v = (i < 64 * KDIM) ? Wc[i] : Wf[i - 64 * KDIM];
        Wb[i] = f2bf(v);
    }
    if (i < STAT_SLOTS * 256) stat_partial[i] = 0.f;
    if (i < N_ATOMS) { counts[i] = 0u; cursors[i] = 0u; }
}

// ---------------------------------------------------------------------------
// Fold BN into per-column scale/shift (kept for the FALLBACK path only; the
// main path computes params inside bn_act_reduce).
// params: [0..63]=scale_c [64..127]=scale_f [128..191]=shift_c [192..255]=shift_f
// ---------------------------------------------------------------------------
__global__ void finalize_stats(const float* __restrict__ stat_partial,
                               const float* __restrict__ gc, const float* __restrict__ btc,
                               const float* __restrict__ gf, const float* __restrict__ btf,
                               float* __restrict__ params)
{
    int t = threadIdx.x;            // 0..127
    bool isf = t >= 64;
    int j = t & 63;
    float s = 0.f, q = 0.f;
    for (int slot = 0; slot < STAT_SLOTS; slot++) {
        const float* sp = stat_partial + (size_t)slot * 256 + (isf ? 128 : 0);
        s += sp[j];
        q += sp[64 + j];
    }
    float mean = s / (float)N_EDGES;
    float var  = q / (float)N_EDGES - mean * mean;
    float inv  = rsqrtf(var + BN_EPS);
    float gamma = isf ? gf[j] : gc[j];
    float beta  = isf ? btf[j] : btc[j];
    float scale = gamma * inv;
    float shift = beta - mean * scale;
    params[t]       = scale;
    params[128 + t] = shift;
}

// ---------------------------------------------------------------------------
// CSR-slot assignment: histogram -> 2-level exclusive scan -> perm.
// init_cursor is ELIMINATED: cursors start at 0 (setup_all) and fill_perm
// adds the base (row_start_local + blk prefix) inline -- identical values.
// ---------------------------------------------------------------------------
__global__ __launch_bounds__(256) void hist_dst(const int* __restrict__ eidx,
                                                unsigned* __restrict__ counts)
{
    int e = blockIdx.x * 256 + threadIdx.x;          // 3125 blocks
    atomicAdd(&counts[eidx[2 * e + 1]], 1u);
}

__global__ __launch_bounds__(256) void scan_a(const unsigned* __restrict__ counts,
                                              unsigned* __restrict__ row_start,
                                              unsigned* __restrict__ blksum)
{
    __shared__ unsigned sh[256];
    const int tid = threadIdx.x;
    const int i = blockIdx.x * 256 + tid;
    unsigned v = (i < N_ATOMS) ? counts[i] : 0u;
    sh[tid] = v;
    __syncthreads();
    for (int off = 1; off < 256; off <<= 1) {
        unsigned t = (tid >= off) ? sh[tid - off] : 0u;
        __syncthreads();
        sh[tid] += t;
        __syncthreads();
    }
    if (i < N_ATOMS) row_start[i] = sh[tid] - v;     // exclusive (block-local)
    if (tid == 255) blksum[blockIdx.x] = sh[tid];
}

__global__ void scan_b(unsigned* __restrict__ blksum)   // 1 block
{
    __shared__ unsigned sh[256];
    const int tid = threadIdx.x;
    unsigned v = (tid < NSCANBLK) ? blksum[tid] : 0u;
    sh[tid] = v;
    __syncthreads();
    for (int off = 1; off < 256; off <<= 1) {
        unsigned t = (tid >= off) ? sh[tid - off] : 0u;
        __syncthreads();
        sh[tid] += t;
        __syncthreads();
    }
    if (tid < NSCANBLK) blksum[tid] = sh[tid] - v;   // exclusive
}

__global__ __launch_bounds__(256) void fill_perm(const int* __restrict__ eidx,
                                                 const unsigned* __restrict__ row_start,
                                                 const unsigned* __restrict__ blksum,
                                                 unsigned* __restrict__ cursors,
                                                 unsigned* __restrict__ perm)
{
    int e = blockIdx.x * 256 + threadIdx.x;
    int d = eidx[2 * e + 1];
    unsigned base = row_start[d] + blksum[d >> 8];   // global row start (L2-hot)
    perm[e] = base + atomicAdd(&cursors[d], 1u);     // coalesced perm write
}

// ---------------------------------------------------------------------------
// Pass 3: streaming gather-reduce WITH FUSED BN-PARAM COMPUTE. Each block
// recomputes the 256 BN params from stat_partial (deterministic, identical
// across blocks; 32KB L2-hot read) -- removes the 1-block finalize dispatch.
// ws_pre rows are in CSR order: each wave (one atom, lane = column) reads a
// CONTIGUOUS run of 256B rows. One plain store per atom; no atomics.
// ---------------------------------------------------------------------------
__global__ __launch_bounds__(256) void bn_act_reduce(
    const unsigned* __restrict__ ws_pre, const unsigned* __restrict__ row_start,
    const unsigned* __restrict__ blksum,
    const float* __restrict__ stat_partial,
    const float* __restrict__ gc, const float* __restrict__ btc,
    const float* __restrict__ gf, const float* __restrict__ btf,
    const float* __restrict__ atom, float* __restrict__ out)
{
    __shared__ float P[256];
    const int tid = threadIdx.x;

    if (tid < 128) {                      // finalize_stats math, verbatim
        bool isf = tid >= 64;
        int j = tid & 63;
        float s = 0.f, q = 0.f;
        for (int slot = 0; slot < STAT_SLOTS; slot++) {
            const float* sp = stat_partial + (size_t)slot * 256 + (isf ? 128 : 0);
            s += sp[j];
            q += sp[64 + j];
        }
        float mean = s / (float)N_EDGES;
        float var  = q / (float)N_EDGES - mean * mean;
        float inv  = rsqrtf(var + BN_EPS);
        float gamma = isf ? gf[j] : gc[j];
        float beta  = isf ? btf[j] : btc[j];
        float scale = gamma * inv;
        float shift = beta - mean * scale;
        P[tid]       = scale;
        P[128 + tid] = shift;
    }
    __syncthreads();

    const int lane = tid & 63;
    const int a    = blockIdx.x * 4 + (tid >> 6);

    const float sc_c = P[lane],      sh_c = P[128 + lane];
    const float sc_f = P[64 + lane], sh_f = P[192 + lane];

    const unsigned jb = row_start[a] + blksum[a >> 8];
    const unsigned je = (a + 1 < N_ATOMS)
                      ? row_start[a + 1] + blksum[(a + 1) >> 8]
                      : (unsigned)N_EDGES;
    const unsigned n  = je - jb;
    const unsigned* base = ws_pre + (size_t)jb * 64 + lane;

    float acc = 0.f;
    unsigned k = 0;
    for (; k + 8 <= n; k += 8) {
        unsigned p[8];
#pragma unroll
        for (int u = 0; u < 8; ++u) p[u] = base[(size_t)(k + u) * 64];
#pragma unroll
        for (int u = 0; u < 8; ++u) acc += msgf(p[u], sc_c, sh_c, sc_f, sh_f);
    }
    for (; k < n; ++k) acc += msgf(base[(size_t)k * 64], sc_c, sh_c, sc_f, sh_f);

    out[(size_t)a * 64 + lane] = atom[(size_t)a * 64 + lane] + acc;
}

// ---------------------------------------------------------------------------
// Fallback path (ws too small): recompute GEMM + atomic scatter (no ws_pre).
// ---------------------------------------------------------------------------
__global__ __launch_bounds__(256) void copy_out(const f32x4* __restrict__ src,
                                                f32x4* __restrict__ dst)
{
    int i = blockIdx.x * blockDim.x + threadIdx.x;
    dst[i] = src[i];
}

__global__ __launch_bounds__(256) void apply_scatter_fb(
    const float* __restrict__ atom, const float* __restrict__ edgef,
    const ushort* __restrict__ Wb, const int* __restrict__ eidx,
    const float* __restrict__ params, float* __restrict__ out)
{
    __shared__ __align__(16) ushort zl[TILE_E * ZSTRIDE];
    const int tid  = threadIdx.x;
    const int lane = tid & 63, wave = tid >> 6;
    const int ch = wave >> 1, rp = wave & 1;
    const int row = lane & 15, quad = lane >> 4;

    bf16x8 bfr[2][2][6];
#pragma unroll
    for (int m = 0; m < 2; ++m)
#pragma unroll
        for (int nt = 0; nt < 2; ++nt)
#pragma unroll
            for (int ks = 0; ks < 6; ++ks)
                bfr[m][nt][ks] = *(const bf16x8*)&Wb[
                    (size_t)(m * 64 + ch * 32 + nt * 16 + row) * KDIM + ks * 32 + quad * 8];

    float scc[2], shc[2], scf[2], shf[2];
#pragma unroll
    for (int nt = 0; nt < 2; ++nt) {
        int c = ch * 32 + nt * 16 + row;
        scc[nt] = params[c];        shc[nt] = params[128 + c];
        scf[nt] = params[64 + c];   shf[nt] = params[192 + c];
    }

    const int t0 = blockIdx.x * TPB;
    for (int tt = 0; tt < TPB; ++tt) {
        const int tilebase = (t0 + tt) * TILE_E;
        f32x4 pre[12];
        gather_issue(atom, edgef, eidx, tilebase, tid, pre);
        __syncthreads();
        gather_commit(pre, zl, tid);
        __syncthreads();
#pragma unroll
        for (int ett = 0; ett < 2; ++ett) {
            const ushort* zb = zl + ((2 * rp + ett) * 16 + row) * ZSTRIDE;
            bf16x8 a[6];
#pragma unroll
            for (int ks = 0; ks < 6; ++ks)
                a[ks] = *(const bf16x8*)&zb[ks * 32 + quad * 8];
            f32x4 acc[2][2];
#pragma unroll
            for (int m = 0; m < 2; ++m)
#pragma unroll
                for (int nt = 0; nt < 2; ++nt)
                    acc[m][nt] = (f32x4){0.f, 0.f, 0.f, 0.f};
#pragma unroll
            for (int ks = 0; ks < 6; ++ks)
#pragma unroll
                for (int m = 0; m < 2; ++m)
#pragma unroll
                    for (int nt = 0; nt < 2; ++nt)
                        acc[m][nt] = __builtin_amdgcn_mfma_f32_16x16x32_bf16(
                            a[ks], bfr[m][nt][ks], acc[m][nt], 0, 0, 0);
#pragma unroll
            for (int nt = 0; nt < 2; ++nt) {
                int c = ch * 32 + nt * 16 + row;
#pragma unroll
                for (int r = 0; r < 4; ++r) {
                    float pc = fmaf(acc[0][nt][r], scc[nt], shc[nt]);
                    float pf = fmaf(acc[1][nt][r], scf[nt], shf[nt]);
                    float sp = fmaxf(pc, 0.f) + __logf(1.f + __expf(-fabsf(pc)));
                    float sg = 1.f / (1.f + __expf(-pf));
                    int eloc = (2 * rp + ett) * 16 + quad * 4 + r;
                    int d = eidx[2 * (tilebase + eloc) + 1];
                    atomicAdd(out + (size_t)d * 64 + c, sp * sg);
                }
            }
        }
    }
}

// ---------------------------------------------------------------------------
extern "C" void kernel_launch(void* const* d_in, const int* in_sizes, int n_in,
                              void* d_out, int out_size, void* d_ws, size_t ws_size,
                              hipStream_t stream)
{
    const float* atom  = (const float*)d_in[0];
    const float* edgef = (const float*)d_in[1];
    const float* Wf    = (const float*)d_in[2];
    const float* gf    = (const float*)d_in[4];
    const float* btf   = (const float*)d_in[5];
    const float* Wc    = (const float*)d_in[6];
    const float* gc    = (const float*)d_in[8];
    const float* btc   = (const float*)d_in[9];
    const int*   eidx  = (const int*)d_in[10];
    float* out = (float*)d_out;

    // workspace layout (ws_pre first keeps everything 16B-aligned)
    unsigned* ws_pre       = (unsigned*)d_ws;                          // N_EDGES*64
    float*    stat_partial = (float*)(ws_pre + (size_t)N_EDGES * 64);  // 8192 f32
    float*    params       = stat_partial + STAT_SLOTS * 256;          // 256 f32
    ushort*   Wb           = (ushort*)(params + 256);                  // 24576 bf16
    unsigned* counts       = (unsigned*)(Wb + 2 * 64 * KDIM);          // 50000
    unsigned* row_start    = counts + N_ATOMS;                         // 50001
    unsigned* blksum       = row_start + N_ATOMS + 1;                  // 256
    unsigned* cursors      = blksum + 256;                             // 50000
    unsigned* perm         = cursors + N_ATOMS;                        // 800000

    const size_t need_full = (size_t)((char*)(perm + N_EDGES) - (char*)d_ws);
    const int full = (ws_size >= need_full) ? 1 : 0;

    setup_all<<<256, 256, 0, stream>>>(Wc, Wf, Wb, stat_partial, counts, cursors);

    if (full) {
        hist_dst<<<N_EDGES / 256, 256, 0, stream>>>(eidx, counts);
        scan_a<<<NSCANBLK, 256, 0, stream>>>(counts, row_start, blksum);
        scan_b<<<1, 256, 0, stream>>>(blksum);
        fill_perm<<<N_EDGES / 256, 256, 0, stream>>>(eidx, row_start, blksum,
                                                     cursors, perm);
        gemm_stats_store<<<GRID1, 256, 0, stream>>>(atom, edgef, Wb, eidx, perm,
                                                    stat_partial, ws_pre, 1);
        bn_act_reduce<<<N_ATOMS / 4, 256, 0, stream>>>(ws_pre, row_start, blksum,
                                                       stat_partial, gc, btc, gf, btf,
                                                       atom, out);
    } else {
        gemm_stats_store<<<GRID1, 256, 0, stream>>>(atom, edgef, Wb, eidx,
                                                    (unsigned*)counts /*unused*/,
                                                    stat_partial, ws_pre, 0);
        finalize_stats<<<1, 128, 0, stream>>>(stat_partial, gc, btc, gf, btf, params);
        copy_out<<<(N_ATOMS * 64 / 4) / 256, 256, 0, stream>>>(
            (const f32x4*)atom, (f32x4*)out);
        apply_scatter_fb<<<GRID1, 256, 0, stream>>>(atom, edgef, Wb, eidx,
                                                    params, out);
    }
}

// Round 6
// 493.718 us; speedup vs baseline: 1.7511x; 1.1179x over previous
//
#include <hip/hip_runtime.h>
#include <hip/hip_bf16.h>
#include <math.h>

// Problem constants
#define N_ATOMS   50000
#define N_EDGES   800000
#define KDIM      192
#define BN_EPS    1e-5f

#define TILE_E     64
#define TPB        5                       // tiles per block (pass 1)
#define NTILES     (N_EDGES / TILE_E)      // 12500
#define GRID1      (NTILES / TPB)          // 2500
#define STAT_SLOTS 32
#define ZSTRIDE    200   // bf16 elems per z row (192 + 8 pad, 16B-aligned rows)
#define NSCANBLK   ((N_ATOMS + 255) / 256) // 196

typedef __attribute__((ext_vector_type(8))) __bf16 bf16x8;
typedef __attribute__((ext_vector_type(4))) float  f32x4;
typedef __attribute__((ext_vector_type(4))) unsigned short u16x4;

__device__ __forceinline__ ushort f2bf(float f) {
    union { float f; unsigned u; } v; v.f = f;
    unsigned u = v.u;
    return (ushort)((u + 0x7FFFu + ((u >> 16) & 1u)) >> 16);
}
__device__ __forceinline__ float bf2f(unsigned hi16) {
    union { unsigned u; float f; } v; v.u = hi16 << 16; return v.f;
}
// BN + sigmoid*softplus message from packed (core | filter<<16) bf16 pair
__device__ __forceinline__ float msgf(unsigned pv, float sc_c, float sh_c,
                                      float sc_f, float sh_f) {
    float pc = fmaf(bf2f(pv & 0xFFFFu), sc_c, sh_c);
    float pf = fmaf(bf2f(pv >> 16),     sc_f, sh_f);
    float sp = fmaxf(pc, 0.f) + __logf(1.f + __expf(-fabsf(pc)));
    float sg = 1.f / (1.f + __expf(-pf));
    return sp * sg;
}

// ---------------------------------------------------------------------------
// Gather split: issue (global loads -> regs) / commit (bf16 convert -> LDS).
// eidx is read directly from global (16 threads/edge share -> L1 broadcast).
// (Round-0 proven structure: 16 lanes read one 256B row contiguously.)
// ---------------------------------------------------------------------------
__device__ __forceinline__ void gather_issue(
    const float* __restrict__ atom, const float* __restrict__ edgef,
    const int* __restrict__ eidx, int tilebase, int tid, f32x4* v)
{
    const int er = tid >> 4, f4 = tid & 15;
#pragma unroll
    for (int it = 0; it < 12; ++it) {
        const int seg = it >> 2;
        const int e   = (it & 3) * 16 + er;
        const float* srcp;
        if (seg == 0)      srcp = atom  + (size_t)eidx[2 * (tilebase + e) + 1] * 64;
        else if (seg == 1) srcp = atom  + (size_t)eidx[2 * (tilebase + e)] * 64;
        else               srcp = edgef + (size_t)(tilebase + e) * 64;
        v[it] = *(const f32x4*)(srcp + f4 * 4);
    }
}

__device__ __forceinline__ void gather_commit(const f32x4* v, ushort* zl, int tid)
{
    const int er = tid >> 4, f4 = tid & 15;
#pragma unroll
    for (int it = 0; it < 12; ++it) {
        const int seg = it >> 2;
        const int e   = (it & 3) * 16 + er;
        u16x4 b;
        b.x = f2bf(v[it].x); b.y = f2bf(v[it].y);
        b.z = f2bf(v[it].z); b.w = f2bf(v[it].w);
        *(u16x4*)&zl[e * ZSTRIDE + seg * 64 + f4 * 4] = b;
    }
}

// ---------------------------------------------------------------------------
// Pass 1 (round-0 163us structure) + INLINE perm build: perml[i] =
// row_start[dst(e)] + rank[e] (replaces the fill_perm kernel; the 320
// scattered L2 reads per block hide under the latency-tolerant main loop).
// Pre-act rows stored PERMUTED to CSR slots so the reduce streams
// sequentially. Bias dropped (cancels under BN).
// One __syncthreads per tile: commit(t) | sync | issue(t+1) | MFMA(t)+store.
// ---------------------------------------------------------------------------
__global__ __launch_bounds__(256) void gemm_stats_store(
    const float* __restrict__ atom, const float* __restrict__ edgef,
    const ushort* __restrict__ Wb, const int* __restrict__ eidx,
    const unsigned* __restrict__ row_start, const unsigned* __restrict__ rank,
    float* __restrict__ stat_partial, unsigned* __restrict__ ws_pre,
    int do_store)
{
    __shared__ __align__(16) ushort zbuf[2][TILE_E * ZSTRIDE]; // 2x25.6KB
    __shared__ unsigned perml[TPB * TILE_E];                   // 1.25KB
    const int tid  = threadIdx.x;
    const int lane = tid & 63, wave = tid >> 6;
    const int ch = wave >> 1, rp = wave & 1;
    const int row = lane & 15, quad = lane >> 4;

    const int t0 = blockIdx.x * TPB;
    if (do_store) {
        for (int i = tid; i < TPB * TILE_E; i += 256) {
            const int e = t0 * TILE_E + i;
            const int d = eidx[2 * e + 1];
            perml[i] = row_start[d] + rank[e];
        }
    }

    bf16x8 bfr[2][2][6];
#pragma unroll
    for (int m = 0; m < 2; ++m)
#pragma unroll
        for (int nt = 0; nt < 2; ++nt)
#pragma unroll
            for (int ks = 0; ks < 6; ++ks)
                bfr[m][nt][ks] = *(const bf16x8*)&Wb[
                    (size_t)(m * 64 + ch * 32 + nt * 16 + row) * KDIM + ks * 32 + quad * 8];

    float s[2][2] = {{0.f, 0.f}, {0.f, 0.f}};
    float q[2][2] = {{0.f, 0.f}, {0.f, 0.f}};

    f32x4 pre[12];
    gather_issue(atom, edgef, eidx, t0 * TILE_E, tid, pre);

    for (int tt = 0; tt < TPB; ++tt) {
        ushort* zl = zbuf[tt & 1];
        gather_commit(pre, zl, tid);
        __syncthreads();   // zl + perml visible; also protects buffer reuse
        if (tt + 1 < TPB)
            gather_issue(atom, edgef, eidx, (t0 + tt + 1) * TILE_E, tid, pre);

#pragma unroll
        for (int ett = 0; ett < 2; ++ett) {
            const ushort* zb = zl + ((2 * rp + ett) * 16 + row) * ZSTRIDE;
            bf16x8 a[6];
#pragma unroll
            for (int ks = 0; ks < 6; ++ks)
                a[ks] = *(const bf16x8*)&zb[ks * 32 + quad * 8];
            f32x4 acc[2][2];
#pragma unroll
            for (int m = 0; m < 2; ++m)
#pragma unroll
                for (int nt = 0; nt < 2; ++nt)
                    acc[m][nt] = (f32x4){0.f, 0.f, 0.f, 0.f};
#pragma unroll
            for (int ks = 0; ks < 6; ++ks)
#pragma unroll
                for (int m = 0; m < 2; ++m)
#pragma unroll
                    for (int nt = 0; nt < 2; ++nt)
                        acc[m][nt] = __builtin_amdgcn_mfma_f32_16x16x32_bf16(
                            a[ks], bfr[m][nt][ks], acc[m][nt], 0, 0, 0);
#pragma unroll
            for (int nt = 0; nt < 2; ++nt) {
                const int c = ch * 32 + nt * 16 + row;
#pragma unroll
                for (int r = 0; r < 4; ++r) {
                    float vc = acc[0][nt][r], vf = acc[1][nt][r];
                    s[0][nt] += vc; q[0][nt] += vc * vc;
                    s[1][nt] += vf; q[1][nt] += vf * vf;
                    if (do_store) {
                        const int eloc = (2 * rp + ett) * 16 + quad * 4 + r;
                        const unsigned pos = perml[tt * TILE_E + eloc];
                        unsigned pack = (unsigned)f2bf(vc) | ((unsigned)f2bf(vf) << 16);
                        ws_pre[(size_t)pos * 64 + c] = pack;  // plain store: L2 merges
                    }
                }
            }
        }
    }

    float* slot = stat_partial + (size_t)(blockIdx.x & (STAT_SLOTS - 1)) * 256;
#pragma unroll
    for (int m = 0; m < 2; ++m)
#pragma unroll
        for (int nt = 0; nt < 2; ++nt) {
            float sv = s[m][nt], qv = q[m][nt];
            sv += __shfl_xor(sv, 16, 64); sv += __shfl_xor(sv, 32, 64);
            qv += __shfl_xor(qv, 16, 64); qv += __shfl_xor(qv, 32, 64);
            if (lane < 16) {
                int c = ch * 32 + nt * 16 + lane;
                atomicAdd(slot + m * 128 + c, sv);
                atomicAdd(slot + m * 128 + 64 + c, qv);
            }
        }
}

// ---------------------------------------------------------------------------
// Fused setup: zero stat_partial + counts, convert weights to bf16.
// ---------------------------------------------------------------------------
__global__ __launch_bounds__(256) void setup_all(
    const float* __restrict__ Wc, const float* __restrict__ Wf,
    ushort* __restrict__ Wb, float* __restrict__ stat_partial,
    unsigned* __restrict__ counts)
{
    int i = blockIdx.x * 256 + threadIdx.x;       // 256 blocks -> 65536 threads
    if (i < 2 * 64 * KDIM) {
        float v = (i < 64 * KDIM) ? Wc[i] : Wf[i - 64 * KDIM];
        Wb[i] = f2bf(v);
    }
    if (i < STAT_SLOTS * 256) stat_partial[i] = 0.f;
    if (i < N_ATOMS) counts[i] = 0u;
}

// ---------------------------------------------------------------------------
// Fold BN into per-column scale/shift (1-block kernel, round-0 form).
// params: [0..63]=scale_c [64..127]=scale_f [128..191]=shift_c [192..255]=shift_f
// ---------------------------------------------------------------------------
__global__ void finalize_stats(const float* __restrict__ stat_partial,
                               const float* __restrict__ gc, const float* __restrict__ btc,
                               const float* __restrict__ gf, const float* __restrict__ btf,
                               float* __restrict__ params)
{
    int t = threadIdx.x;            // 0..127
    bool isf = t >= 64;
    int j = t & 63;
    float s = 0.f, q = 0.f;
    for (int slot = 0; slot < STAT_SLOTS; slot++) {
        const float* sp = stat_partial + (size_t)slot * 256 + (isf ? 128 : 0);
        s += sp[j];
        q += sp[64 + j];
    }
    float mean = s / (float)N_EDGES;
    float var  = q / (float)N_EDGES - mean * mean;
    float inv  = rsqrtf(var + BN_EPS);
    float gamma = isf ? gf[j] : gc[j];
    float beta  = isf ? btf[j] : btc[j];
    float scale = gamma * inv;
    float shift = beta - mean * scale;
    params[t]       = scale;
    params[128 + t] = shift;
}

// ---------------------------------------------------------------------------
// CSR-slot assignment WITHOUT a second atomic pass:
//   hist_rank: rank[e] = atomicAdd(&counts[d],1)  (histogram atomic's return
//              value IS the within-dst rank -- fill_perm's 800k atomics and
//              the cursors array are eliminated)
//   scan_a/scan_b: 2-level exclusive scan of counts
//   init_row: globalize row_start (+ sentinel); gemm adds rank inline.
// ---------------------------------------------------------------------------
__global__ __launch_bounds__(256) void hist_rank(const int* __restrict__ eidx,
                                                 unsigned* __restrict__ counts,
                                                 unsigned* __restrict__ rank)
{
    int e = blockIdx.x * 256 + threadIdx.x;          // 3125 blocks
    rank[e] = atomicAdd(&counts[eidx[2 * e + 1]], 1u);
}

__global__ __launch_bounds__(256) void scan_a(const unsigned* __restrict__ counts,
                                              unsigned* __restrict__ row_start,
                                              unsigned* __restrict__ blksum)
{
    __shared__ unsigned sh[256];
    const int tid = threadIdx.x;
    const int i = blockIdx.x * 256 + tid;
    unsigned v = (i < N_ATOMS) ? counts[i] : 0u;
    sh[tid] = v;
    __syncthreads();
    for (int off = 1; off < 256; off <<= 1) {
        unsigned t = (tid >= off) ? sh[tid - off] : 0u;
        __syncthreads();
        sh[tid] += t;
        __syncthreads();
    }
    if (i < N_ATOMS) row_start[i] = sh[tid] - v;     // exclusive (block-local)
    if (tid == 255) blksum[blockIdx.x] = sh[tid];
}

__global__ void scan_b(unsigned* __restrict__ blksum)   // 1 block
{
    __shared__ unsigned sh[256];
    const int tid = threadIdx.x;
    unsigned v = (tid < NSCANBLK) ? blksum[tid] : 0u;
    sh[tid] = v;
    __syncthreads();
    for (int off = 1; off < 256; off <<= 1) {
        unsigned t = (tid >= off) ? sh[tid - off] : 0u;
        __syncthreads();
        sh[tid] += t;
        __syncthreads();
    }
    if (tid < NSCANBLK) blksum[tid] = sh[tid] - v;   // exclusive
}

__global__ __launch_bounds__(256) void init_row(unsigned* __restrict__ row_start,
                                                const unsigned* __restrict__ blksum)
{
    int i = blockIdx.x * 256 + threadIdx.x;
    if (i < N_ATOMS) row_start[i] += blksum[i >> 8];  // globalize
    if (i == 0) row_start[N_ATOMS] = N_EDGES;         // sentinel
}

// ---------------------------------------------------------------------------
// Pass 3: streaming gather-reduce (round-0 form). ws_pre rows are in CSR
// order: each wave (one atom, lane = column) reads a CONTIGUOUS run of 256B
// rows. One plain store per atom; no atomics, no index indirection.
// ---------------------------------------------------------------------------
__global__ __launch_bounds__(256) void bn_act_reduce(
    const unsigned* __restrict__ ws_pre, const unsigned* __restrict__ row_start,
    const float* __restrict__ atom, const float* __restrict__ params,
    float* __restrict__ out)
{
    const int lane = threadIdx.x & 63;
    const int a    = blockIdx.x * 4 + (threadIdx.x >> 6);

    const float sc_c = params[lane],      sh_c = params[128 + lane];
    const float sc_f = params[64 + lane], sh_f = params[192 + lane];

    const unsigned jb = row_start[a];
    const unsigned n  = row_start[a + 1] - jb;
    const unsigned* base = ws_pre + (size_t)jb * 64 + lane;

    float acc = 0.f;
    unsigned k = 0;
    for (; k + 8 <= n; k += 8) {
        unsigned p[8];
#pragma unroll
        for (int u = 0; u < 8; ++u) p[u] = base[(size_t)(k + u) * 64];
#pragma unroll
        for (int u = 0; u < 8; ++u) acc += msgf(p[u], sc_c, sh_c, sc_f, sh_f);
    }
    for (; k < n; ++k) acc += msgf(base[(size_t)k * 64], sc_c, sh_c, sc_f, sh_f);

    out[(size_t)a * 64 + lane] = atom[(size_t)a * 64 + lane] + acc;
}

// ---------------------------------------------------------------------------
// Fallback path (ws too small): recompute GEMM + atomic scatter (no ws_pre).
// ---------------------------------------------------------------------------
__global__ __launch_bounds__(256) void copy_out(const f32x4* __restrict__ src,
                                                f32x4* __restrict__ dst)
{
    int i = blockIdx.x * blockDim.x + threadIdx.x;
    dst[i] = src[i];
}

__global__ __launch_bounds__(256) void apply_scatter_fb(
    const float* __restrict__ atom, const float* __restrict__ edgef,
    const ushort* __restrict__ Wb, const int* __restrict__ eidx,
    const float* __restrict__ params, float* __restrict__ out)
{
    __shared__ __align__(16) ushort zl[TILE_E * ZSTRIDE];
    const int tid  = threadIdx.x;
    const int lane = tid & 63, wave = tid >> 6;
    const int ch = wave >> 1, rp = wave & 1;
    const int row = lane & 15, quad = lane >> 4;

    bf16x8 bfr[2][2][6];
#pragma unroll
    for (int m = 0; m < 2; ++m)
#pragma unroll
        for (int nt = 0; nt < 2; ++nt)
#pragma unroll
            for (int ks = 0; ks < 6; ++ks)
                bfr[m][nt][ks] = *(const bf16x8*)&Wb[
                    (size_t)(m * 64 + ch * 32 + nt * 16 + row) * KDIM + ks * 32 + quad * 8];

    float scc[2], shc[2], scf[2], shf[2];
#pragma unroll
    for (int nt = 0; nt < 2; ++nt) {
        int c = ch * 32 + nt * 16 + row;
        scc[nt] = params[c];        shc[nt] = params[128 + c];
        scf[nt] = params[64 + c];   shf[nt] = params[192 + c];
    }

    const int t0 = blockIdx.x * TPB;
    for (int tt = 0; tt < TPB; ++tt) {
        const int tilebase = (t0 + tt) * TILE_E;
        f32x4 pre[12];
        gather_issue(atom, edgef, eidx, tilebase, tid, pre);
        __syncthreads();
        gather_commit(pre, zl, tid);
        __syncthreads();
#pragma unroll
        for (int ett = 0; ett < 2; ++ett) {
            const ushort* zb = zl + ((2 * rp + ett) * 16 + row) * ZSTRIDE;
            bf16x8 a[6];
#pragma unroll
            for (int ks = 0; ks < 6; ++ks)
                a[ks] = *(const bf16x8*)&zb[ks * 32 + quad * 8];
            f32x4 acc[2][2];
#pragma unroll
            for (int m = 0; m < 2; ++m)
#pragma unroll
                for (int nt = 0; nt < 2; ++nt)
                    acc[m][nt] = (f32x4){0.f, 0.f, 0.f, 0.f};
#pragma unroll
            for (int ks = 0; ks < 6; ++ks)
#pragma unroll
                for (int m = 0; m < 2; ++m)
#pragma unroll
                    for (int nt = 0; nt < 2; ++nt)
                        acc[m][nt] = __builtin_amdgcn_mfma_f32_16x16x32_bf16(
                            a[ks], bfr[m][nt][ks], acc[m][nt], 0, 0, 0);
#pragma unroll
            for (int nt = 0; nt < 2; ++nt) {
                int c = ch * 32 + nt * 16 + row;
#pragma unroll
                for (int r = 0; r < 4; ++r) {
                    float pc = fmaf(acc[0][nt][r], scc[nt], shc[nt]);
                    float pf = fmaf(acc[1][nt][r], scf[nt], shf[nt]);
                    float sp = fmaxf(pc, 0.f) + __logf(1.f + __expf(-fabsf(pc)));
                    float sg = 1.f / (1.f + __expf(-pf));
                    int eloc = (2 * rp + ett) * 16 + quad * 4 + r;
                    int d = eidx[2 * (tilebase + eloc) + 1];
                    atomicAdd(out + (size_t)d * 64 + c, sp * sg);
                }
            }
        }
    }
}

// ---------------------------------------------------------------------------
extern "C" void kernel_launch(void* const* d_in, const int* in_sizes, int n_in,
                              void* d_out, int out_size, void* d_ws, size_t ws_size,
                              hipStream_t stream)
{
    const float* atom  = (const float*)d_in[0];
    const float* edgef = (const float*)d_in[1];
    const float* Wf    = (const float*)d_in[2];
    const float* gf    = (const float*)d_in[4];
    const float* btf   = (const float*)d_in[5];
    const float* Wc    = (const float*)d_in[6];
    const float* gc    = (const float*)d_in[8];
    const float* btc   = (const float*)d_in[9];
    const int*   eidx  = (const int*)d_in[10];
    float* out = (float*)d_out;

    // workspace layout (ws_pre first keeps everything 16B-aligned)
    unsigned* ws_pre       = (unsigned*)d_ws;                          // N_EDGES*64
    float*    stat_partial = (float*)(ws_pre + (size_t)N_EDGES * 64);  // 8192 f32
    float*    params       = stat_partial + STAT_SLOTS * 256;          // 256 f32
    ushort*   Wb           = (ushort*)(params + 256);                  // 24576 bf16
    unsigned* counts       = (unsigned*)(Wb + 2 * 64 * KDIM);          // 50000
    unsigned* row_start    = counts + N_ATOMS;                         // 50001
    unsigned* blksum       = row_start + N_ATOMS + 1;                  // 256
    unsigned* rank         = blksum + 256;                             // 800000

    const size_t need_full = (size_t)((char*)(rank + N_EDGES) - (char*)d_ws);
    const int full = (ws_size >= need_full) ? 1 : 0;

    setup_all<<<256, 256, 0, stream>>>(Wc, Wf, Wb, stat_partial, counts);

    if (full) {
        hist_rank<<<N_EDGES / 256, 256, 0, stream>>>(eidx, counts, rank);
        scan_a<<<NSCANBLK, 256, 0, stream>>>(counts, row_start, blksum);
        scan_b<<<1, 256, 0, stream>>>(blksum);
        init_row<<<NSCANBLK, 256, 0, stream>>>(row_start, blksum);
        gemm_stats_store<<<GRID1, 256, 0, stream>>>(atom, edgef, Wb, eidx,
                                                    row_start, rank,
                                                    stat_partial, ws_pre, 1);
        finalize_stats<<<1, 128, 0, stream>>>(stat_partial, gc, btc, gf, btf, params);
        bn_act_reduce<<<N_ATOMS / 4, 256, 0, stream>>>(ws_pre, row_start,
                                                       atom, params, out);
    } else {
        gemm_stats_store<<<GRID1, 256, 0, stream>>>(atom, edgef, Wb, eidx,
                                                    (unsigned*)counts /*unused*/,
                                                    (unsigned*)counts /*unused*/,
                                                    stat_partial, ws_pre, 0);
        finalize_stats<<<1, 128, 0, stream>>>(stat_partial, gc, btc, gf, btf, params);
        copy_out<<<(N_ATOMS * 64 / 4) / 256, 256, 0, stream>>>(
            (const f32x4*)atom, (f32x4*)out);
        apply_scatter_fb<<<GRID1, 256, 0, stream>>>(atom, edgef, Wb, eidx,
                                                    params, out);
    }
}